// Round 5
// baseline (21423.723 us; speedup 1.0000x reference)
//
#include <hip/hip_runtime.h>

typedef _Float16 f16;
typedef __attribute__((ext_vector_type(8))) _Float16 f16x8;
typedef __attribute__((ext_vector_type(4))) float f32x4;

#define E_TOTAL 160000
#define NN 20000
#define NGRAPH 64

__device__ __forceinline__ void gl_lds16(const void* g, void* l) {
    __builtin_amdgcn_global_load_lds((const __attribute__((address_space(1))) void*)g,
                                     (__attribute__((address_space(3))) void*)l, 16, 0, 0);
}

struct BFrag { f16x8 v[4][2]; };   // [ni][ks], all indices compile-time

// ---------------- fp16 MFMA GEMM, 256x256 tile, BK=64, 8 waves ----------------
// A (activations) staged in LDS (2x32KB dbuf, swizzled, global_load_lds w16).
// B (weights, Bt[N,K] row-major) loaded DIRECT from global (L2-resident) into
// registers, double-banked. Counted vmcnt(12) = 4 A-stages + 8 B-loads per tile.
// Two barriers per K-step (WAR-safe). AUXU/AUXX epilogue fusions as before.
template <int RELU, int AUXU, int AUXX>
__global__ __launch_bounds__(512, 4) void hgemm3(
    int M, int N, int K,
    const f16* __restrict__ A, int lda,
    const f16* __restrict__ Bt,
    f16* __restrict__ C, int ldc,
    const float* __restrict__ bias,
    const f16* __restrict__ utab, const int* __restrict__ uidx,
    const float* __restrict__ x9, const int* __restrict__ xidx, const float* __restrict__ W9)
{
    __shared__ __align__(16) char Ash[2][32768];
    __shared__ float Ws9[AUXX ? 2304 : 1];   // 9 x 256

    const int tid  = threadIdx.x;
    const int lane = tid & 63;
    const int w    = tid >> 6;            // 0..7
    const int bm = blockIdx.y * 256;
    const int bn = blockIdx.x * 256;
    const int wm = (w >> 2) * 128;        // 2 waves along M
    const int wn = (w & 3) * 64;          // 4 waves along N
    const int fr = lane & 15;
    const int kq = lane >> 4;

    const char* Ab = (const char*)A;
    const char* Bb = (const char*)Bt;
    const size_t lda2 = (size_t)lda * 2;
    const size_t ldb2 = (size_t)K * 2;

    f32x4 acc[8][4] = {};

    // A staging: 32KB per K-step = 8 waves x 4 chunks x 1KB (rows cch*8..cch*8+7)
    size_t offA[4];
    int ldsoff[4];
#pragma unroll
    for (int i = 0; i < 4; ++i) {
        int cch = w * 4 + i;
        int L = cch * 1024 + lane * 16;
        int row = L >> 7;
        int scb = (L & 127) ^ ((row & 7) << 4);  // pre-swizzled global source
        offA[i] = (size_t)(bm + row) * lda2 + scb;
        ldsoff[i] = cch * 1024;
    }

    // B direct-load bases: lane reads 16B at row (bn+wn+ni*16+fr), byte k*2
    const char* bbase[4];
#pragma unroll
    for (int ni = 0; ni < 4; ++ni)
        bbase[ni] = Bb + (size_t)(bn + wn + ni * 16 + fr) * ldb2 + kq * 16;

    const int NT = K >> 6;

    auto stageA = [&](int t, int buf) {
        size_t kb = (size_t)t << 7;   // t*64 k * 2B
#pragma unroll
        for (int i = 0; i < 4; ++i)
            gl_lds16(Ab + offA[i] + kb, Ash[buf] + ldsoff[i]);
    };
    auto loadB = [&](BFrag& d, int t) {
#pragma unroll
        for (int ni = 0; ni < 4; ++ni)
#pragma unroll
            for (int ks = 0; ks < 2; ++ks)
                d.v[ni][ks] = *(const f16x8*)(bbase[ni] + (((size_t)t) << 7) + ks * 64);
    };
    auto compute = [&](const char* As, const BFrag& bc) {
#pragma unroll
        for (int p = 0; p < 4; ++p) {        // 4 phases: mi pairs
            f16x8 a0[2], a1[2];
#pragma unroll
            for (int q = 0; q < 2; ++q) {
                int r = wm + (p * 2 + q) * 16 + fr;
                int sw = (r & 7) << 4;
                a0[q] = *(const f16x8*)(As + r * 128 + ((kq * 16) ^ sw));
                a1[q] = *(const f16x8*)(As + r * 128 + ((64 + kq * 16) ^ sw));
            }
            __builtin_amdgcn_s_setprio(1);
#pragma unroll
            for (int q = 0; q < 2; ++q) {
                int mi = p * 2 + q;
#pragma unroll
                for (int ni = 0; ni < 4; ++ni)
                    acc[mi][ni] = __builtin_amdgcn_mfma_f32_16x16x32_f16(a0[q], bc.v[ni][0], acc[mi][ni], 0, 0, 0);
#pragma unroll
                for (int ni = 0; ni < 4; ++ni)
                    acc[mi][ni] = __builtin_amdgcn_mfma_f32_16x16x32_f16(a1[q], bc.v[ni][1], acc[mi][ni], 0, 0, 0);
            }
            __builtin_amdgcn_s_setprio(0);
            __builtin_amdgcn_sched_barrier(0);
        }
    };
    auto step = [&](int t, int buf, const BFrag& bc, BFrag& bnx) {
        if (t + 1 < NT) {
            stageA(t + 1, buf ^ 1);
            loadB(bnx, t + 1);
            __builtin_amdgcn_sched_barrier(0);
            asm volatile("s_waitcnt vmcnt(12)" ::: "memory");  // tile t landed; t+1 in flight
        } else {
            asm volatile("s_waitcnt vmcnt(0)" ::: "memory");
        }
        __builtin_amdgcn_s_barrier();          // tile-t data visible to all waves
        __builtin_amdgcn_sched_barrier(0);
        compute(Ash[buf], bc);
        __builtin_amdgcn_s_barrier();          // all reads of Ash[buf] done (WAR-safe)
    };

    BFrag bf0, bf1;
    stageA(0, 0);
    loadB(bf0, 0);
    int t = 0;
    for (; t + 2 <= NT; t += 2) {
        step(t,     0, bf0, bf1);
        step(t + 1, 1, bf1, bf0);
    }
    if (t < NT) step(t, t & 1, bf0, bf1);   // NT odd (e.g. NT=1)

    if (AUXX) {
        for (int i = tid; i < 9 * 256; i += 512)
            Ws9[i] = W9[(size_t)(i >> 8) * N + bn + (i & 255)];
        __syncthreads();
    }

    // C/D layout: col = lane&15, row = kq*4 + reg
#pragma unroll
    for (int mi = 0; mi < 8; ++mi) {
        int r0 = bm + wm + mi * 16 + kq * 4;
#pragma unroll
        for (int r = 0; r < 4; ++r) {
            int grow = r0 + r;
            if (grow >= M) continue;
            int ub = 0;
            if (AUXU) ub = uidx[grow];
            float xv[9];
            if (AUXX) {
                int xi = xidx ? xidx[grow] : grow;
#pragma unroll
                for (int q = 0; q < 9; ++q) xv[q] = x9[(size_t)xi * 9 + q];
            }
#pragma unroll
            for (int ni = 0; ni < 4; ++ni) {
                int lcol = wn + ni * 16 + fr;
                int col = bn + lcol;
                float v = acc[mi][ni][r] + bias[col];
                if (AUXU) v += (float)utab[(size_t)ub * N + col];
                if (AUXX) {
                    float s = 0.f;
#pragma unroll
                    for (int q = 0; q < 9; ++q) s = fmaf(xv[q], Ws9[q * 256 + lcol], s);
                    v += s;
                }
                if (RELU) v = fmaxf(v, 0.f);
                C[(size_t)grow * ldc + col] = (f16)v;
            }
        }
    }
}

// ---- weight slice transpose: Wt[n][k] = W[(r0+k)*N + n], k<Ksub, pad to Kp with 0 ----
__global__ void k_wt(const float* __restrict__ W, f16* __restrict__ Wt,
                     int r0, int Ksub, int N, int Kp)
{
    size_t t = (size_t)blockIdx.x * 256 + threadIdx.x;
    if (t >= (size_t)N * Kp) return;
    int n = (int)(t / Kp), k = (int)(t % Kp);
    Wt[t] = (k < Ksub) ? (f16)W[(size_t)(r0 + k) * N + n] : (f16)0.f;
}

// ---- u2h = f16(u @ Wsel + bsel)  split-K ----
__global__ __launch_bounds__(256) void k_u2(const float* __restrict__ u,
                                            const float* __restrict__ Wsel,
                                            const float* __restrict__ bsel,
                                            f16* __restrict__ u2h)
{
    __shared__ float us[4096];
    __shared__ float red[4][64];
    const int g = blockIdx.y;
    const int c0 = blockIdx.x * 64;
    const int col = threadIdx.x & 63;
    const int kp = threadIdx.x >> 6;
    for (int i = threadIdx.x; i < 4096; i += 256) us[i] = u[(size_t)g * 4096 + i];
    __syncthreads();
    float acc = 0.f;
    for (int k = kp * 1024; k < kp * 1024 + 1024; ++k)
        acc = fmaf(us[k], Wsel[(size_t)k * 256 + c0 + col], acc);
    red[kp][col] = acc;
    __syncthreads();
    if (kp == 0) {
        float v = red[0][col] + red[1][col] + red[2][col] + red[3][col] + bsel[c0 + col];
        u2h[(size_t)g * 256 + c0 + col] = (f16)v;
    }
}

// ---- per-edge gather: feat64 = [x[row](9), x[col](9), ea(1), 0-pad], ebat = batch[row] ----
__global__ void k_gather19(int e0, int Ce,
                           const float* __restrict__ x, const float* __restrict__ eattr,
                           const int* __restrict__ ei, const int* __restrict__ batch,
                           f16* __restrict__ feat, int* __restrict__ ebat)
{
    size_t t = (size_t)blockIdx.x * 256 + threadIdx.x;
    if (t >= (size_t)Ce * 64) return;
    int i = (int)(t >> 6), j = (int)(t & 63);
    int e = e0 + i;
    float v = 0.f;
    if (j < 9)        v = x[ei[e] * 9 + j];
    else if (j < 18)  v = x[ei[E_TOTAL + e] * 9 + (j - 9)];
    else if (j == 18) v = eattr[e];
    else if (j == 19) ebat[i] = batch[ei[e]];
    feat[t] = (f16)v;
}

__global__ void k_scatter(int e0, int Ce, const f16* __restrict__ h2,
                          const int* __restrict__ ei, float* __restrict__ ssum)
{
    size_t t = (size_t)blockIdx.x * 256 + threadIdx.x;
    if (t >= (size_t)Ce * 512) return;
    int i = (int)(t >> 9), j = (int)(t & 511);
    atomicAdd(ssum + (size_t)ei[e0 + i] * 512 + j, (float)h2[t]);
}

__global__ void k_cnt(const int* __restrict__ ei, float* __restrict__ cnt)
{
    int t = blockIdx.x * 256 + threadIdx.x;
    if (t < E_TOTAL) atomicAdd(cnt + ei[t], 1.0f);
}

__global__ void k_agg(const float* __restrict__ ssum, const float* __restrict__ cnt,
                      f16* __restrict__ agg)
{
    size_t t = (size_t)blockIdx.x * 256 + threadIdx.x;
    if (t >= (size_t)NN * 512) return;
    int n = (int)(t >> 9);
    agg[t] = (f16)(ssum[t] / fmaxf(cnt[n], 1.f));
}

__global__ void k_final(const f16* __restrict__ z1, const float* __restrict__ W,
                        const float* __restrict__ b, float* __restrict__ out)
{
    int gt = blockIdx.x * 256 + threadIdx.x;
    int row = gt >> 6;
    int lane = threadIdx.x & 63;
    if (row >= NN) return;
    float s = 0.f;
#pragma unroll
    for (int c = lane; c < 512; c += 64) s += (float)z1[(size_t)row * 512 + c] * W[c];
#pragma unroll
    for (int off = 32; off; off >>= 1) s += __shfl_down(s, off);
    if (lane == 0) out[row] = s + b[0];
}

// ---------------- launch ----------------

extern "C" void kernel_launch(void* const* d_in, const int* in_sizes, int n_in,
                              void* d_out, int out_size, void* d_ws, size_t ws_size,
                              hipStream_t stream)
{
    const float* x     = (const float*)d_in[0];
    const float* eattr = (const float*)d_in[1];
    const float* u     = (const float*)d_in[2];
    const int*   ei    = (const int*)d_in[3];
    const int*   batch = (const int*)d_in[4];
    const float* Wsel  = (const float*)d_in[5];
    const float* bsel  = (const float*)d_in[6];
    const float* eW1 = (const float*)d_in[7],  * eb1 = (const float*)d_in[8];
    const float* eW2 = (const float*)d_in[9],  * eb2 = (const float*)d_in[10];
    const float* eW3 = (const float*)d_in[11], * eb3 = (const float*)d_in[12];
    const float* eW4 = (const float*)d_in[13], * eb4 = (const float*)d_in[14];
    const float* eW5 = (const float*)d_in[15], * eb5 = (const float*)d_in[16];
    const float* n1W1 = (const float*)d_in[17], * n1b1 = (const float*)d_in[18];
    const float* n1W2 = (const float*)d_in[19], * n1b2 = (const float*)d_in[20];
    const float* n2W1 = (const float*)d_in[21], * n2b1 = (const float*)d_in[22];
    const float* n2W2 = (const float*)d_in[23], * n2b2 = (const float*)d_in[24];
    float* out = (float*)d_out;

    char* ws = (char*)d_ws;
    size_t off = 0;
    auto alc = [&](size_t bytes) { char* p = ws + off; off += (bytes + 255) & ~(size_t)255; return p; };

    float* ssum  = (float*)alc((size_t)NN * 512 * 4);
    float* cnt   = (float*)alc((size_t)NN * 4);
    float* zbias = (float*)alc(1024 * 4);
    f16* u2h     = (f16*)alc((size_t)256 * 256 * 2);      // 64 valid rows, padded to 256
    f16* ubias_e = (f16*)alc((size_t)64 * 1024 * 2);
    f16* ubias_n = (f16*)alc((size_t)64 * 512 * 2);
    f16* eW1t19  = (f16*)alc((size_t)1024 * 64 * 2);
    f16* eW1ut   = (f16*)alc((size_t)1024 * 256 * 2);
    f16* eW2t    = (f16*)alc((size_t)1024 * 1024 * 2);
    f16* eW3t    = (f16*)alc((size_t)1024 * 1024 * 2);
    f16* eW4t    = (f16*)alc((size_t)1024 * 1024 * 2);
    f16* eW5t    = (f16*)alc((size_t)512 * 1024 * 2);
    f16* n1W1et  = (f16*)alc((size_t)512 * 512 * 2);
    f16* n1W2t   = (f16*)alc((size_t)512 * 512 * 2);
    f16* n2W1et  = (f16*)alc((size_t)512 * 512 * 2);
    f16* n2W1ut  = (f16*)alc((size_t)512 * 256 * 2);
    f16* agg     = (f16*)alc((size_t)20224 * 512 * 2);
    f16* z1      = (f16*)alc((size_t)20224 * 512 * 2);
    size_t fixed = off;

    // chunk region: per-edge = feat64 (128B) + buf1 (2048B) + buf2 (2048B) + ebat (4B)
    size_t per_edge = 64 * 2 + 1024 * 2 + 1024 * 2 + 4;
    size_t avail = ws_size > fixed ? ws_size - fixed : 0;
    long long Cll = (long long)(avail / per_edge);
    int C = (int)((Cll / 256) * 256);
    if (C > E_TOTAL) C = E_TOTAL;   // 160000 = 625*256
    if (C < 256) C = 256;

    f16* featc = (f16*)(ws + fixed);
    f16* buf1  = featc + (size_t)C * 64;
    f16* buf2  = buf1 + (size_t)C * 1024;
    int* ebat  = (int*)(buf2 + (size_t)C * 1024);

    size_t zlen = (size_t)((char*)zbias - (char*)ssum) + 1024 * 4;
    hipMemsetAsync(ssum, 0, zlen, stream);

    auto wt = [&](const float* W, f16* Wt, int r0, int Ksub, int N, int Kp) {
        size_t tot = (size_t)N * Kp;
        k_wt<<<(unsigned)((tot + 255) / 256), 256, 0, stream>>>(W, Wt, r0, Ksub, N, Kp);
    };
    wt(eW1, eW1t19, 0, 19, 1024, 64);
    wt(eW1, eW1ut, 19, 256, 1024, 256);
    wt(eW2, eW2t, 0, 1024, 1024, 1024);
    wt(eW3, eW3t, 0, 1024, 1024, 1024);
    wt(eW4, eW4t, 0, 1024, 1024, 1024);
    wt(eW5, eW5t, 0, 1024, 512, 1024);
    wt(n1W1, n1W1et, 9, 512, 512, 512);
    wt(n1W2, n1W2t, 0, 512, 512, 512);
    wt(n2W1, n2W1et, 9, 512, 512, 512);
    wt(n2W1, n2W1ut, 521, 256, 512, 256);

    k_u2<<<dim3(4, NGRAPH), 256, 0, stream>>>(u, Wsel, bsel, u2h);
    k_cnt<<<(E_TOTAL + 255) / 256, 256, 0, stream>>>(ei, cnt);

    // u-contribution tables (include the layer bias)
    hgemm3<0,0,0><<<dim3(4, 1), 512, 0, stream>>>(64, 1024, 256, u2h, 256, eW1ut,
        ubias_e, 1024, eb1, nullptr, nullptr, nullptr, nullptr, nullptr);
    hgemm3<0,0,0><<<dim3(2, 1), 512, 0, stream>>>(64, 512, 256, u2h, 256, n2W1ut,
        ubias_n, 512, n2b1, nullptr, nullptr, nullptr, nullptr, nullptr);

    for (int e0 = 0; e0 < E_TOTAL; e0 += C) {
        int Ce = E_TOTAL - e0 < C ? E_TOTAL - e0 : C;
        int gy = (Ce + 255) / 256;

        k_gather19<<<(unsigned)(((size_t)Ce * 64 + 255) / 256), 256, 0, stream>>>(
            e0, Ce, x, eattr, ei, batch, featc, ebat);

        hgemm3<1,1,0><<<dim3(4, gy), 512, 0, stream>>>(Ce, 1024, 64, featc, 64, eW1t19,
            buf1, 1024, zbias, ubias_e, ebat, nullptr, nullptr, nullptr);
        hgemm3<1,0,0><<<dim3(4, gy), 512, 0, stream>>>(Ce, 1024, 1024, buf1, 1024, eW2t,
            buf2, 1024, eb2, nullptr, nullptr, nullptr, nullptr, nullptr);
        hgemm3<1,0,0><<<dim3(4, gy), 512, 0, stream>>>(Ce, 1024, 1024, buf2, 1024, eW3t,
            buf1, 1024, eb3, nullptr, nullptr, nullptr, nullptr, nullptr);
        hgemm3<1,0,0><<<dim3(4, gy), 512, 0, stream>>>(Ce, 1024, 1024, buf1, 1024, eW4t,
            buf2, 1024, eb4, nullptr, nullptr, nullptr, nullptr, nullptr);
        hgemm3<0,0,0><<<dim3(2, gy), 512, 0, stream>>>(Ce, 512, 1024, buf2, 1024, eW5t,
            buf1, 512, eb5, nullptr, nullptr, nullptr, nullptr, nullptr);   // e -> buf1

        hgemm3<1,0,1><<<dim3(2, gy), 512, 0, stream>>>(Ce, 512, 512, buf1, 512, n1W1et,
            buf2, 512, n1b1, nullptr, nullptr, x, ei + E_TOTAL + e0, n1W1);  // h1 -> buf2
        hgemm3<1,0,0><<<dim3(2, gy), 512, 0, stream>>>(Ce, 512, 512, buf2, 512, n1W2t,
            buf1, 512, n1b2, nullptr, nullptr, nullptr, nullptr, nullptr);   // h2 -> buf1

        k_scatter<<<(unsigned)(((size_t)Ce * 512 + 255) / 256), 256, 0, stream>>>(
            e0, Ce, buf1, ei, ssum);
    }

    // readout
    k_agg<<<(unsigned)(((size_t)NN * 512 + 255) / 256), 256, 0, stream>>>(ssum, cnt, agg);
    hgemm3<1,1,1><<<dim3(2, 79), 512, 0, stream>>>(NN, 512, 512, agg, 512, n2W1et,
        z1, 512, zbias, ubias_n, batch, x, nullptr, n2W1);
    k_final<<<(NN * 64 + 255) / 256, 256, 0, stream>>>(z1, n2W2, n2b2, out);
}

// Round 6
// 2372.670 us; speedup vs baseline: 9.0294x; 9.0294x over previous
//
#include <hip/hip_runtime.h>

typedef _Float16 f16;
typedef __attribute__((ext_vector_type(8))) _Float16 f16x8;
typedef __attribute__((ext_vector_type(4))) float f32x4;

#define E_TOTAL 160000
#define NN 20000
#define NGRAPH 64

__device__ __forceinline__ void gl_lds16(const void* g, void* l) {
    __builtin_amdgcn_global_load_lds((const __attribute__((address_space(1))) void*)g,
                                     (__attribute__((address_space(3))) void*)l, 16, 0, 0);
}

// ---------------- fp16 MFMA GEMM, 256x256 tile, BK=64, 8 waves, counted-vmcnt ----------------
// C[M,N] = act(A[M,lda] @ Bt[N,K]^T + bias [+aux]).  K mult of 64, N mult of 256 or 512-with-2panels.
// Per K-step: [stage t+1 issue][vmcnt(8)][barrier][compute t][barrier]  (sound, never drains mid-loop)
// AUXU: += utab[uidx[row]*N + col]   AUXX: += dot(x9[xi*9..], W9[q*N + col])
// SCAT: atomicAdd(sout[sidx[row]*N + col], v) instead of C write.
template <int RELU, int AUXU, int AUXX, int SCAT>
__global__ __launch_bounds__(512, 2) void hgemm2(
    int M, int N, int K,
    const f16* __restrict__ A, int lda,
    const f16* __restrict__ Bt,
    f16* __restrict__ C, int ldc,
    const float* __restrict__ bias,
    const f16* __restrict__ utab, const int* __restrict__ uidx,
    const float* __restrict__ x9, const int* __restrict__ xidx, const float* __restrict__ W9,
    float* __restrict__ sout, const int* __restrict__ sidx)
{
    __shared__ __align__(16) char Ash[2][32768];
    __shared__ __align__(16) char Bsh[2][32768];
    __shared__ float Ws9[AUXX ? 2304 : 1];   // 9 x 256

    const int tid  = threadIdx.x;
    const int lane = tid & 63;
    const int w    = tid >> 6;            // 0..7
    const int bm = blockIdx.y * 256;
    const int bn = blockIdx.x * 256;
    const int wm = (w >> 2) * 128;        // 2 waves along M
    const int wn = (w & 3) * 64;          // 4 waves along N
    const int fr = lane & 15;
    const int kq = lane >> 4;

    const char* Ab = (const char*)A;
    const char* Bb = (const char*)Bt;
    const size_t lda2 = (size_t)lda * 2;
    const size_t ldb2 = (size_t)K * 2;

    f32x4 acc[8][4] = {};

    // staging: 32 KB per operand per K-step = 8 waves x 4 insts x 1 KB
    size_t offA[4], offB[4];
    int ldsoff[4];
#pragma unroll
    for (int i = 0; i < 4; ++i) {
        int cch = w * 4 + i;
        int L = cch * 1024 + lane * 16;
        int row = L >> 7;
        int scb = (L & 127) ^ ((row & 7) << 4);  // pre-swizzled global source
        offA[i] = (size_t)(bm + row) * lda2 + scb;
        offB[i] = (size_t)(bn + row) * ldb2 + scb;
        ldsoff[i] = cch * 1024;                  // wave-uniform LDS base
    }

    const int NT = K >> 6;

    // prologue: stage tile 0 into buf 0
#pragma unroll
    for (int i = 0; i < 4; ++i) gl_lds16(Ab + offA[i], Ash[0] + ldsoff[i]);
#pragma unroll
    for (int i = 0; i < 4; ++i) gl_lds16(Bb + offB[i], Bsh[0] + ldsoff[i]);

    int cur = 0;
    for (int t = 0; t < NT; ++t) {
        if (t + 1 < NT) {
            size_t kb = (size_t)(t + 1) << 7;   // k0*2 bytes
#pragma unroll
            for (int i = 0; i < 4; ++i) gl_lds16(Ab + offA[i] + kb, Ash[cur ^ 1] + ldsoff[i]);
#pragma unroll
            for (int i = 0; i < 4; ++i) gl_lds16(Bb + offB[i] + kb, Bsh[cur ^ 1] + ldsoff[i]);
            asm volatile("s_waitcnt vmcnt(8)" ::: "memory");   // tile t landed; t+1 in flight
        } else {
            asm volatile("s_waitcnt vmcnt(0)" ::: "memory");
        }
        __builtin_amdgcn_s_barrier();            // tile-t data visible to all waves
        __builtin_amdgcn_sched_barrier(0);

        const char* As = Ash[cur];
        const char* Bs = Bsh[cur];

        f16x8 bv[2][4];
#pragma unroll
        for (int ks = 0; ks < 2; ++ks) {
            const int cb = (ks * 32 + kq * 8) * 2;
#pragma unroll
            for (int ni = 0; ni < 4; ++ni) {
                int r = wn + ni * 16 + fr;
                bv[ks][ni] = *(const f16x8*)(Bs + r * 128 + (cb ^ ((r & 7) << 4)));
            }
        }
        __builtin_amdgcn_s_setprio(1);
#pragma unroll
        for (int mi = 0; mi < 8; ++mi) {
            int r = wm + mi * 16 + fr;
            int sw = (r & 7) << 4;
            f16x8 a0 = *(const f16x8*)(As + r * 128 + ((kq * 16) ^ sw));
            f16x8 a1 = *(const f16x8*)(As + r * 128 + ((64 + kq * 16) ^ sw));
#pragma unroll
            for (int ni = 0; ni < 4; ++ni)
                acc[mi][ni] = __builtin_amdgcn_mfma_f32_16x16x32_f16(a0, bv[0][ni], acc[mi][ni], 0, 0, 0);
#pragma unroll
            for (int ni = 0; ni < 4; ++ni)
                acc[mi][ni] = __builtin_amdgcn_mfma_f32_16x16x32_f16(a1, bv[1][ni], acc[mi][ni], 0, 0, 0);
        }
        __builtin_amdgcn_s_setprio(0);
        __builtin_amdgcn_s_barrier();            // all reads of buf[cur] done (WAR-safe for next stage)
        cur ^= 1;
    }

    if (AUXX) {
        for (int i = tid; i < 9 * 256; i += 512)
            Ws9[i] = W9[(size_t)(i >> 8) * N + bn + (i & 255)];
        __syncthreads();
    }

    // C/D layout: col = lane&15, row = kq*4 + reg
#pragma unroll
    for (int mi = 0; mi < 8; ++mi) {
        int r0 = bm + wm + mi * 16 + kq * 4;
#pragma unroll
        for (int r = 0; r < 4; ++r) {
            int grow = r0 + r;
            if (grow >= M) continue;
            int ub = 0;
            if (AUXU) ub = uidx[grow];
            int sb = 0;
            if (SCAT) sb = sidx[grow];
            float xv[9];
            if (AUXX) {
                int xi = xidx ? xidx[grow] : grow;
#pragma unroll
                for (int q = 0; q < 9; ++q) xv[q] = x9[(size_t)xi * 9 + q];
            }
#pragma unroll
            for (int ni = 0; ni < 4; ++ni) {
                int lcol = wn + ni * 16 + fr;
                int col = bn + lcol;
                float v = acc[mi][ni][r] + bias[col];
                if (AUXU) v += (float)utab[(size_t)ub * N + col];
                if (AUXX) {
                    float s = 0.f;
#pragma unroll
                    for (int q = 0; q < 9; ++q) s = fmaf(xv[q], Ws9[q * 256 + lcol], s);
                    v += s;
                }
                if (RELU) v = fmaxf(v, 0.f);
                if (SCAT) {
                    atomicAdd(sout + (size_t)sb * N + col, v);
                } else {
                    C[(size_t)grow * ldc + col] = (f16)v;
                }
            }
        }
    }
}

// ---- weight slice transpose: Wt[n][k] = W[(r0+k)*N + n], k<Ksub, pad to Kp with 0 ----
__global__ void k_wt(const float* __restrict__ W, f16* __restrict__ Wt,
                     int r0, int Ksub, int N, int Kp)
{
    size_t t = (size_t)blockIdx.x * 256 + threadIdx.x;
    if (t >= (size_t)N * Kp) return;
    int n = (int)(t / Kp), k = (int)(t % Kp);
    Wt[t] = (k < Ksub) ? (f16)W[(size_t)(r0 + k) * N + n] : (f16)0.f;
}

// ---- plain f32 -> f16 copy ----
__global__ void k_cvt(const float* __restrict__ W, f16* __restrict__ Wt, int n)
{
    int t = blockIdx.x * 256 + threadIdx.x;
    if (t < n) Wt[t] = (f16)W[t];
}

// ---- combo bias: cb[b] = n1b1[b] + sum_c eb5[c] * n1W1[(9+c)*512 + b] ----
__global__ void k_cbias(const float* __restrict__ n1W1, const float* __restrict__ eb5,
                        const float* __restrict__ n1b1, float* __restrict__ cb)
{
    int b = blockIdx.x * 256 + threadIdx.x;
    if (b >= 512) return;
    float s = n1b1[b];
    for (int c = 0; c < 512; ++c) s = fmaf(eb5[c], n1W1[(size_t)(9 + c) * 512 + b], s);
    cb[b] = s;
}

// ---- u2h = f16(u @ Wsel + bsel)  split-K ----
__global__ __launch_bounds__(256) void k_u2(const float* __restrict__ u,
                                            const float* __restrict__ Wsel,
                                            const float* __restrict__ bsel,
                                            f16* __restrict__ u2h)
{
    __shared__ float us[4096];
    __shared__ float red[4][64];
    const int g = blockIdx.y;
    const int c0 = blockIdx.x * 64;
    const int col = threadIdx.x & 63;
    const int kp = threadIdx.x >> 6;
    for (int i = threadIdx.x; i < 4096; i += 256) us[i] = u[(size_t)g * 4096 + i];
    __syncthreads();
    float acc = 0.f;
    for (int k = kp * 1024; k < kp * 1024 + 1024; ++k)
        acc = fmaf(us[k], Wsel[(size_t)k * 256 + c0 + col], acc);
    red[kp][col] = acc;
    __syncthreads();
    if (kp == 0) {
        float v = red[0][col] + red[1][col] + red[2][col] + red[3][col] + bsel[c0 + col];
        u2h[(size_t)g * 256 + c0 + col] = (f16)v;
    }
}

// ---- per-edge gather: feat64 = [x[row](9), x[col](9), ea(1), 0-pad], ebat = batch[row] ----
__global__ void k_gather19(int e0, int Ce,
                           const float* __restrict__ x, const float* __restrict__ eattr,
                           const int* __restrict__ ei, const int* __restrict__ batch,
                           f16* __restrict__ feat, int* __restrict__ ebat)
{
    size_t t = (size_t)blockIdx.x * 256 + threadIdx.x;
    if (t >= (size_t)Ce * 64) return;
    int i = (int)(t >> 6), j = (int)(t & 63);
    int e = e0 + i;
    float v = 0.f;
    if (j < 9)        v = x[ei[e] * 9 + j];
    else if (j < 18)  v = x[ei[E_TOTAL + e] * 9 + (j - 9)];
    else if (j == 18) v = eattr[e];
    else if (j == 19) ebat[i] = batch[ei[e]];
    feat[t] = (f16)v;
}

__global__ void k_cnt(const int* __restrict__ ei, float* __restrict__ cnt)
{
    int t = blockIdx.x * 256 + threadIdx.x;
    if (t < E_TOTAL) atomicAdd(cnt + ei[t], 1.0f);
}

__global__ void k_agg(const float* __restrict__ ssum, const float* __restrict__ cnt,
                      f16* __restrict__ agg)
{
    size_t t = (size_t)blockIdx.x * 256 + threadIdx.x;
    if (t >= (size_t)NN * 512) return;
    int n = (int)(t >> 9);
    agg[t] = (f16)(ssum[t] / fmaxf(cnt[n], 1.f));
}

__global__ void k_final(const f16* __restrict__ z1, const float* __restrict__ W,
                        const float* __restrict__ b, float* __restrict__ out)
{
    int gt = blockIdx.x * 256 + threadIdx.x;
    int row = gt >> 6;
    int lane = threadIdx.x & 63;
    if (row >= NN) return;
    float s = 0.f;
#pragma unroll
    for (int c = lane; c < 512; c += 64) s += (float)z1[(size_t)row * 512 + c] * W[c];
#pragma unroll
    for (int off = 32; off; off >>= 1) s += __shfl_down(s, off);
    if (lane == 0) out[row] = s + b[0];
}

// ---------------- launch ----------------

extern "C" void kernel_launch(void* const* d_in, const int* in_sizes, int n_in,
                              void* d_out, int out_size, void* d_ws, size_t ws_size,
                              hipStream_t stream)
{
    const float* x     = (const float*)d_in[0];
    const float* eattr = (const float*)d_in[1];
    const float* u     = (const float*)d_in[2];
    const int*   ei    = (const int*)d_in[3];
    const int*   batch = (const int*)d_in[4];
    const float* Wsel  = (const float*)d_in[5];
    const float* bsel  = (const float*)d_in[6];
    const float* eW1 = (const float*)d_in[7],  * eb1 = (const float*)d_in[8];
    const float* eW2 = (const float*)d_in[9],  * eb2 = (const float*)d_in[10];
    const float* eW3 = (const float*)d_in[11], * eb3 = (const float*)d_in[12];
    const float* eW4 = (const float*)d_in[13], * eb4 = (const float*)d_in[14];
    const float* eW5 = (const float*)d_in[15], * eb5 = (const float*)d_in[16];
    const float* n1W1 = (const float*)d_in[17], * n1b1 = (const float*)d_in[18];
    const float* n1W2 = (const float*)d_in[19], * n1b2 = (const float*)d_in[20];
    const float* n2W1 = (const float*)d_in[21], * n2b1 = (const float*)d_in[22];
    const float* n2W2 = (const float*)d_in[23], * n2b2 = (const float*)d_in[24];
    float* out = (float*)d_out;

    char* ws = (char*)d_ws;
    size_t off = 0;
    auto alc = [&](size_t bytes) { char* p = ws + off; off += (bytes + 255) & ~(size_t)255; return p; };

    float* ssum  = (float*)alc((size_t)NN * 512 * 4);
    float* cnt   = (float*)alc((size_t)NN * 4);
    float* zbias = (float*)alc(1024 * 4);
    float* cbias = (float*)alc(512 * 4);
    f16* u2h     = (f16*)alc((size_t)256 * 256 * 2);      // 64 valid rows, padded to 256
    f16* ubias_e = (f16*)alc((size_t)64 * 1024 * 2);
    f16* ubias_n = (f16*)alc((size_t)64 * 512 * 2);
    f16* eW1t19  = (f16*)alc((size_t)1024 * 64 * 2);
    f16* eW1ut   = (f16*)alc((size_t)1024 * 256 * 2);
    f16* eW2t    = (f16*)alc((size_t)1024 * 1024 * 2);
    f16* eW3t    = (f16*)alc((size_t)1024 * 1024 * 2);
    f16* eW4t    = (f16*)alc((size_t)1024 * 1024 * 2);
    f16* eW5h    = (f16*)alc((size_t)1024 * 512 * 2);     // eW5 as f16 [1024][512] (= Bt for combo GEMM)
    f16* combo_t = (f16*)alc((size_t)512 * 1024 * 2);     // (eW5 @ n1W1[9:521])^T as Bt [512][1024]
    f16* n1W1et  = (f16*)alc((size_t)512 * 512 * 2);
    f16* n1W2t   = (f16*)alc((size_t)512 * 512 * 2);
    f16* n2W1et  = (f16*)alc((size_t)512 * 512 * 2);
    f16* n2W1ut  = (f16*)alc((size_t)512 * 256 * 2);
    f16* agg     = (f16*)alc((size_t)20224 * 512 * 2);
    f16* z1      = (f16*)alc((size_t)20224 * 512 * 2);
    size_t fixed = off;

    // chunk region: per-edge = feat64 (128B) + buf1 (2048B) + buf2 (2048B) + ebat (4B)
    size_t per_edge = 64 * 2 + 1024 * 2 + 1024 * 2 + 4;
    size_t avail = ws_size > fixed ? ws_size - fixed : 0;
    long long Cmax = (long long)(avail / per_edge);
    int C;
    if (Cmax >= E_TOTAL)      C = E_TOTAL;                       // single chunk (2500 blocks, 2% tail)
    else if (Cmax >= 16384)   C = (int)((Cmax / 16384) * 16384); // perfect 256-block rounds
    else                      C = (int)((Cmax / 256) * 256);
    if (C < 256) C = 256;

    f16* featc = (f16*)(ws + fixed);
    f16* buf1  = featc + (size_t)C * 64;
    f16* buf2  = buf1 + (size_t)C * 1024;
    int* ebat  = (int*)(buf2 + (size_t)C * 1024);

    // zero ssum, cnt, zbias (contiguous; cbias computed by kernel)
    size_t zlen = (size_t)((char*)zbias - (char*)ssum) + 1024 * 4;
    hipMemsetAsync(ssum, 0, zlen, stream);

    auto wt = [&](const float* W, f16* Wt, int r0, int Ksub, int N, int Kp) {
        size_t tot = (size_t)N * Kp;
        k_wt<<<(unsigned)((tot + 255) / 256), 256, 0, stream>>>(W, Wt, r0, Ksub, N, Kp);
    };
    wt(eW1, eW1t19, 0, 19, 1024, 64);
    wt(eW1, eW1ut, 19, 256, 1024, 256);
    wt(eW2, eW2t, 0, 1024, 1024, 1024);
    wt(eW3, eW3t, 0, 1024, 1024, 1024);
    wt(eW4, eW4t, 0, 1024, 1024, 1024);
    wt(n1W1, n1W1et, 9, 512, 512, 512);
    wt(n1W2, n1W2t, 0, 512, 512, 512);
    wt(n2W1, n2W1et, 9, 512, 512, 512);
    wt(n2W1, n2W1ut, 521, 256, 512, 256);
    k_cvt<<<(1024 * 512 + 255) / 256, 256, 0, stream>>>(eW5, eW5h, 1024 * 512);

    k_u2<<<dim3(4, NGRAPH), 256, 0, stream>>>(u, Wsel, bsel, u2h);
    k_cnt<<<(E_TOTAL + 255) / 256, 256, 0, stream>>>(ei, cnt);
    k_cbias<<<2, 256, 0, stream>>>(n1W1, eb5, n1b1, cbias);

    // u-contribution tables (include the layer bias)
    hgemm2<0,0,0,0><<<dim3(4, 1), 512, 0, stream>>>(64, 1024, 256, u2h, 256, eW1ut,
        ubias_e, 1024, eb1, nullptr, nullptr, nullptr, nullptr, nullptr, nullptr, nullptr);
    hgemm2<0,0,0,0><<<dim3(2, 1), 512, 0, stream>>>(64, 512, 256, u2h, 256, n2W1ut,
        ubias_n, 512, n2b1, nullptr, nullptr, nullptr, nullptr, nullptr, nullptr, nullptr);

    // combo_t[b][a] = sum_c n1W1[9+c][b] * eW5[a][c]   (M=512 rows b, N=1024 cols a, K=512)
    hgemm2<0,0,0,0><<<dim3(4, 2), 512, 0, stream>>>(512, 1024, 512, n1W1et, 512, eW5h,
        combo_t, 1024, zbias, nullptr, nullptr, nullptr, nullptr, nullptr, nullptr, nullptr);

    for (int e0 = 0; e0 < E_TOTAL; e0 += C) {
        int Ce = E_TOTAL - e0 < C ? E_TOTAL - e0 : C;
        int gy = (Ce + 255) / 256;

        k_gather19<<<(unsigned)(((size_t)Ce * 64 + 255) / 256), 256, 0, stream>>>(
            e0, Ce, x, eattr, ei, batch, featc, ebat);

        hgemm2<1,1,0,0><<<dim3(4, gy), 512, 0, stream>>>(Ce, 1024, 64, featc, 64, eW1t19,
            buf1, 1024, zbias, ubias_e, ebat, nullptr, nullptr, nullptr, nullptr, nullptr);
        hgemm2<1,0,0,0><<<dim3(4, gy), 512, 0, stream>>>(Ce, 1024, 1024, buf1, 1024, eW2t,
            buf2, 1024, eb2, nullptr, nullptr, nullptr, nullptr, nullptr, nullptr, nullptr);
        hgemm2<1,0,0,0><<<dim3(4, gy), 512, 0, stream>>>(Ce, 1024, 1024, buf2, 1024, eW3t,
            buf1, 1024, eb3, nullptr, nullptr, nullptr, nullptr, nullptr, nullptr, nullptr);
        hgemm2<1,0,0,0><<<dim3(4, gy), 512, 0, stream>>>(Ce, 1024, 1024, buf1, 1024, eW4t,
            buf2, 1024, eb4, nullptr, nullptr, nullptr, nullptr, nullptr, nullptr, nullptr);

        // h1 = relu(x[col]@n1W1[0:9] + (buf2)@combo + cbias)   (eW5+n1W1 folded)
        hgemm2<1,0,1,0><<<dim3(2, gy), 512, 0, stream>>>(Ce, 512, 1024, buf2, 1024, combo_t,
            buf1, 512, cbias, nullptr, nullptr, x, ei + E_TOTAL + e0, n1W1, nullptr, nullptr);

        // h2 = relu(h1@n1W2 + n1b2), scatter-add into ssum fused in epilogue
        hgemm2<1,0,0,1><<<dim3(2, gy), 512, 0, stream>>>(Ce, 512, 512, buf1, 512, n1W2t,
            nullptr, 512, n1b2, nullptr, nullptr, nullptr, nullptr, nullptr, ssum, ei + e0);
    }

    // readout
    k_agg<<<(unsigned)(((size_t)NN * 512 + 255) / 256), 256, 0, stream>>>(ssum, cnt, agg);
    hgemm2<1,1,1,0><<<dim3(2, 79), 512, 0, stream>>>(NN, 512, 512, agg, 512, n2W1et,
        z1, 512, zbias, ubias_n, batch, x, nullptr, n2W1, nullptr, nullptr);
    k_final<<<(NN * 64 + 255) / 256, 256, 0, stream>>>(z1, n2W2, n2b2, out);
}

// Round 7
// 2347.598 us; speedup vs baseline: 9.1258x; 1.0107x over previous
//
#include <hip/hip_runtime.h>

typedef _Float16 f16;
typedef __attribute__((ext_vector_type(8))) _Float16 f16x8;
typedef __attribute__((ext_vector_type(4))) float f32x4;

#define E_TOTAL 160000
#define NN 20000
#define NGRAPH 64

__device__ __forceinline__ void gl_lds16(const void* g, void* l) {
    __builtin_amdgcn_global_load_lds((const __attribute__((address_space(1))) void*)g,
                                     (__attribute__((address_space(3))) void*)l, 16, 0, 0);
}

#define MFMA16(a, b, c) __builtin_amdgcn_mfma_f32_16x16x32_f16((a), (b), (c), 0, 0, 0)
#define LGKM0 do { asm volatile("s_waitcnt lgkmcnt(0)" ::: "memory"); \
                   __builtin_amdgcn_sched_barrier(0); } while (0)
#define VMW4  asm volatile("s_waitcnt vmcnt(4)" ::: "memory")
#define VMW0  asm volatile("s_waitcnt vmcnt(0)" ::: "memory")
#define SBAR  __builtin_amdgcn_s_barrier()

// ---------------- fp16 MFMA GEMM, 256x256 tile, BK=64, 8 waves, 8-phase schedule -------------
// C[M,N] = act(A[M,lda] @ Bt[N,K]^T + bias [+aux]).  K mult of 64, N mult of 256.
// LDS: [dbuf][khalf] 16KB half-tiles of 256 rows x 32k (64B rows, slot^=(row>>1)&3 swizzle).
// Per tile: 4 phases {ds_read frags | stage 1 half-tile | barrier | lgkm0 | 16 MFMA | [vm4] | barrier}
// Stages in consumption order A-k0,B-k0,A-k1,B-k1; steady-state waits are vmcnt(4) only (T3+T4).
// AUXU: += utab[uidx[row]*N+col]  AUXX: += dot(x9[xi*9..], W9[q*N+col])  SCAT: atomicAdd to sout.
template <int RELU, int AUXU, int AUXX, int SCAT>
__global__ __launch_bounds__(512, 2) void hgemm8(
    int M, int N, int K,
    const f16* __restrict__ A, int lda,
    const f16* __restrict__ Bt,
    f16* __restrict__ C, int ldc,
    const float* __restrict__ bias,
    const f16* __restrict__ utab, const int* __restrict__ uidx,
    const float* __restrict__ x9, const int* __restrict__ xidx, const float* __restrict__ W9,
    float* __restrict__ sout, const int* __restrict__ sidx)
{
    __shared__ __align__(16) char Ash[2][2][16384];
    __shared__ __align__(16) char Bsh[2][2][16384];
    __shared__ float Ws9[AUXX ? 2304 : 1];   // 9 x 256

    const int tid  = threadIdx.x;
    const int lane = tid & 63;
    const int w    = tid >> 6;            // 0..7
    const int bm = blockIdx.y * 256;
    const int bn = blockIdx.x * 256;
    const int wm = (w >> 2) * 128;        // 2 waves along M
    const int wn = (w & 3) * 64;          // 4 waves along N
    const int fr = lane & 15;
    const int kq = lane >> 4;

    const char* Ab = (const char*)A;
    const char* Bb = (const char*)Bt;
    const size_t lda2 = (size_t)lda * 2;
    const size_t ldb2 = (size_t)K * 2;

    f32x4 acc[8][4] = {};

    // ds_read offsets within a 16KB half-buffer: row r has 64B, slot swizzle s = kq ^ ((r>>1)&3)
    int aoff[8], boff[4];
#pragma unroll
    for (int mi = 0; mi < 8; ++mi) {
        int r = wm + mi * 16 + fr;
        aoff[mi] = r * 64 + ((kq ^ ((r >> 1) & 3)) << 4);
    }
#pragma unroll
    for (int ni = 0; ni < 4; ++ni) {
        int r = wn + ni * 16 + fr;
        boff[ni] = r * 64 + ((kq ^ ((r >> 1) & 3)) << 4);
    }

    // staging: 16KB half-tile = 512 thr x 2 x 16B; LDS linear dest, pre-swizzled global source
    int sdest[2];
    size_t gsrcA[2], gsrcB[2];
#pragma unroll
    for (int i = 0; i < 2; ++i) {
        int L = i * 8192 + tid * 16;
        int row = L >> 6;
        int s = (L >> 4) & 3;
        int sw = (s ^ ((row >> 1) & 3)) << 4;
        sdest[i] = L;
        gsrcA[i] = (size_t)(bm + row) * lda2 + sw;
        gsrcB[i] = (size_t)(bn + row) * ldb2 + sw;
    }

    const int NT = K >> 6;

    auto stageA = [&](int t, int h, int buf) {
        size_t kb = (size_t)t * 128 + h * 64;
#pragma unroll
        for (int i = 0; i < 2; ++i)
            gl_lds16(Ab + gsrcA[i] + kb, &Ash[buf][h][0] + sdest[i]);
    };
    auto stageB = [&](int t, int h, int buf) {
        size_t kb = (size_t)t * 128 + h * 64;
#pragma unroll
        for (int i = 0; i < 2; ++i)
            gl_lds16(Bb + gsrcB[i] + kb, &Bsh[buf][h][0] + sdest[i]);
    };

    // prologue: stage tile 0 (4 half-tiles, consumption order), wait first two
    stageA(0, 0, 0); stageB(0, 0, 0); stageA(0, 1, 0); stageB(0, 1, 0);
    VMW4;
    SBAR;

    for (int t = 0; t < NT; ++t) {
        const int cur = t & 1, nxt = cur ^ 1;
        const bool pre = (t + 1 < NT);
        const char* A0 = &Ash[cur][0][0];
        const char* A1 = &Ash[cur][1][0];
        const char* B0 = &Bsh[cur][0][0];
        const char* B1 = &Bsh[cur][1][0];

        // ---- phase 0: ks=0, mi 0-3 ----
        f16x8 a0[4], b0[4];
#pragma unroll
        for (int i = 0; i < 4; ++i) a0[i] = *(const f16x8*)(A0 + aoff[i]);
#pragma unroll
        for (int i = 0; i < 4; ++i) b0[i] = *(const f16x8*)(B0 + boff[i]);
        if (pre) stageA(t + 1, 0, nxt);
        SBAR;
        LGKM0;
        __builtin_amdgcn_s_setprio(1);
#pragma unroll
        for (int mi = 0; mi < 4; ++mi)
#pragma unroll
            for (int ni = 0; ni < 4; ++ni)
                acc[mi][ni] = MFMA16(a0[mi], b0[ni], acc[mi][ni]);
        __builtin_amdgcn_s_setprio(0);
        SBAR;

        // ---- phase 1: ks=0, mi 4-7 ----
        f16x8 a1[4];
#pragma unroll
        for (int i = 0; i < 4; ++i) a1[i] = *(const f16x8*)(A0 + aoff[4 + i]);
        if (pre) stageB(t + 1, 0, nxt);
        SBAR;
        LGKM0;
        __builtin_amdgcn_s_setprio(1);
#pragma unroll
        for (int mi = 0; mi < 4; ++mi)
#pragma unroll
            for (int ni = 0; ni < 4; ++ni)
                acc[4 + mi][ni] = MFMA16(a1[mi], b0[ni], acc[4 + mi][ni]);
        __builtin_amdgcn_s_setprio(0);
        if (pre) { VMW4; } else { VMW0; }   // A-k1(t), B-k1(t) landed
        SBAR;

        // ---- phase 2: ks=1, mi 0-3 ----
        f16x8 a2[4], b2[4];
#pragma unroll
        for (int i = 0; i < 4; ++i) a2[i] = *(const f16x8*)(A1 + aoff[i]);
#pragma unroll
        for (int i = 0; i < 4; ++i) b2[i] = *(const f16x8*)(B1 + boff[i]);
        if (pre) stageA(t + 1, 1, nxt);
        SBAR;
        LGKM0;
        __builtin_amdgcn_s_setprio(1);
#pragma unroll
        for (int mi = 0; mi < 4; ++mi)
#pragma unroll
            for (int ni = 0; ni < 4; ++ni)
                acc[mi][ni] = MFMA16(a2[mi], b2[ni], acc[mi][ni]);
        __builtin_amdgcn_s_setprio(0);
        SBAR;

        // ---- phase 3: ks=1, mi 4-7 ----
        f16x8 a3[4];
#pragma unroll
        for (int i = 0; i < 4; ++i) a3[i] = *(const f16x8*)(A1 + aoff[4 + i]);
        if (pre) stageB(t + 1, 1, nxt);
        SBAR;
        LGKM0;
        __builtin_amdgcn_s_setprio(1);
#pragma unroll
        for (int mi = 0; mi < 4; ++mi)
#pragma unroll
            for (int ni = 0; ni < 4; ++ni)
                acc[4 + mi][ni] = MFMA16(a3[mi], b2[ni], acc[4 + mi][ni]);
        __builtin_amdgcn_s_setprio(0);
        if (pre) { VMW4; }                  // A-k0(t+1), B-k0(t+1) landed
        SBAR;
    }

    if (AUXX) {
        for (int i = tid; i < 9 * 256; i += 512)
            Ws9[i] = W9[(size_t)(i >> 8) * N + bn + (i & 255)];
        __syncthreads();
    }

    // C/D layout: col = lane&15, row = kq*4 + reg
#pragma unroll
    for (int mi = 0; mi < 8; ++mi) {
        int r0 = bm + wm + mi * 16 + kq * 4;
#pragma unroll
        for (int r = 0; r < 4; ++r) {
            int grow = r0 + r;
            if (grow >= M) continue;
            int ub = 0;
            if (AUXU) ub = uidx[grow];
            int sb = 0;
            if (SCAT) sb = sidx[grow];
            float xv[9];
            if (AUXX) {
                int xi = xidx ? xidx[grow] : grow;
#pragma unroll
                for (int q = 0; q < 9; ++q) xv[q] = x9[(size_t)xi * 9 + q];
            }
#pragma unroll
            for (int ni = 0; ni < 4; ++ni) {
                int lcol = wn + ni * 16 + fr;
                int col = bn + lcol;
                float v = acc[mi][ni][r] + bias[col];
                if (AUXU) v += (float)utab[(size_t)ub * N + col];
                if (AUXX) {
                    float s = 0.f;
#pragma unroll
                    for (int q = 0; q < 9; ++q) s = fmaf(xv[q], Ws9[q * 256 + lcol], s);
                    v += s;
                }
                if (RELU) v = fmaxf(v, 0.f);
                if (SCAT) {
                    atomicAdd(sout + (size_t)sb * N + col, v);
                } else {
                    C[(size_t)grow * ldc + col] = (f16)v;
                }
            }
        }
    }
}

// ---- weight slice transpose: Wt[n][k] = W[(r0+k)*N + n], k<Ksub, pad to Kp with 0 ----
__global__ void k_wt(const float* __restrict__ W, f16* __restrict__ Wt,
                     int r0, int Ksub, int N, int Kp)
{
    size_t t = (size_t)blockIdx.x * 256 + threadIdx.x;
    if (t >= (size_t)N * Kp) return;
    int n = (int)(t / Kp), k = (int)(t % Kp);
    Wt[t] = (k < Ksub) ? (f16)W[(size_t)(r0 + k) * N + n] : (f16)0.f;
}

// ---- plain f32 -> f16 copy ----
__global__ void k_cvt(const float* __restrict__ W, f16* __restrict__ Wt, int n)
{
    int t = blockIdx.x * 256 + threadIdx.x;
    if (t < n) Wt[t] = (f16)W[t];
}

// ---- combo bias: cb[b] = n1b1[b] + sum_c eb5[c] * n1W1[(9+c)*512 + b] ----
__global__ void k_cbias(const float* __restrict__ n1W1, const float* __restrict__ eb5,
                        const float* __restrict__ n1b1, float* __restrict__ cb)
{
    int b = blockIdx.x * 256 + threadIdx.x;
    if (b >= 512) return;
    float s = n1b1[b];
    for (int c = 0; c < 512; ++c) s = fmaf(eb5[c], n1W1[(size_t)(9 + c) * 512 + b], s);
    cb[b] = s;
}

// ---- u2h = f16(u @ Wsel + bsel)  split-K ----
__global__ __launch_bounds__(256) void k_u2(const float* __restrict__ u,
                                            const float* __restrict__ Wsel,
                                            const float* __restrict__ bsel,
                                            f16* __restrict__ u2h)
{
    __shared__ float us[4096];
    __shared__ float red[4][64];
    const int g = blockIdx.y;
    const int c0 = blockIdx.x * 64;
    const int col = threadIdx.x & 63;
    const int kp = threadIdx.x >> 6;
    for (int i = threadIdx.x; i < 4096; i += 256) us[i] = u[(size_t)g * 4096 + i];
    __syncthreads();
    float acc = 0.f;
    for (int k = kp * 1024; k < kp * 1024 + 1024; ++k)
        acc = fmaf(us[k], Wsel[(size_t)k * 256 + c0 + col], acc);
    red[kp][col] = acc;
    __syncthreads();
    if (kp == 0) {
        float v = red[0][col] + red[1][col] + red[2][col] + red[3][col] + bsel[c0 + col];
        u2h[(size_t)g * 256 + c0 + col] = (f16)v;
    }
}

// ---- per-edge gather: feat64 = [x[row](9), x[col](9), ea(1), 0-pad], ebat = batch[row] ----
__global__ void k_gather19(int e0, int Ce,
                           const float* __restrict__ x, const float* __restrict__ eattr,
                           const int* __restrict__ ei, const int* __restrict__ batch,
                           f16* __restrict__ feat, int* __restrict__ ebat)
{
    size_t t = (size_t)blockIdx.x * 256 + threadIdx.x;
    if (t >= (size_t)Ce * 64) return;
    int i = (int)(t >> 6), j = (int)(t & 63);
    int e = e0 + i;
    float v = 0.f;
    if (j < 9)        v = x[ei[e] * 9 + j];
    else if (j < 18)  v = x[ei[E_TOTAL + e] * 9 + (j - 9)];
    else if (j == 18) v = eattr[e];
    else if (j == 19) ebat[i] = batch[ei[e]];
    feat[t] = (f16)v;
}

__global__ void k_cnt(const int* __restrict__ ei, float* __restrict__ cnt)
{
    int t = blockIdx.x * 256 + threadIdx.x;
    if (t < E_TOTAL) atomicAdd(cnt + ei[t], 1.0f);
}

__global__ void k_agg(const float* __restrict__ ssum, const float* __restrict__ cnt,
                      f16* __restrict__ agg)
{
    size_t t = (size_t)blockIdx.x * 256 + threadIdx.x;
    if (t >= (size_t)NN * 512) return;
    int n = (int)(t >> 9);
    agg[t] = (f16)(ssum[t] / fmaxf(cnt[n], 1.f));
}

__global__ void k_final(const f16* __restrict__ z1, const float* __restrict__ W,
                        const float* __restrict__ b, float* __restrict__ out)
{
    int gt = blockIdx.x * 256 + threadIdx.x;
    int row = gt >> 6;
    int lane = threadIdx.x & 63;
    if (row >= NN) return;
    float s = 0.f;
#pragma unroll
    for (int c = lane; c < 512; c += 64) s += (float)z1[(size_t)row * 512 + c] * W[c];
#pragma unroll
    for (int off = 32; off; off >>= 1) s += __shfl_down(s, off);
    if (lane == 0) out[row] = s + b[0];
}

// ---------------- launch ----------------

extern "C" void kernel_launch(void* const* d_in, const int* in_sizes, int n_in,
                              void* d_out, int out_size, void* d_ws, size_t ws_size,
                              hipStream_t stream)
{
    const float* x     = (const float*)d_in[0];
    const float* eattr = (const float*)d_in[1];
    const float* u     = (const float*)d_in[2];
    const int*   ei    = (const int*)d_in[3];
    const int*   batch = (const int*)d_in[4];
    const float* Wsel  = (const float*)d_in[5];
    const float* bsel  = (const float*)d_in[6];
    const float* eW1 = (const float*)d_in[7],  * eb1 = (const float*)d_in[8];
    const float* eW2 = (const float*)d_in[9],  * eb2 = (const float*)d_in[10];
    const float* eW3 = (const float*)d_in[11], * eb3 = (const float*)d_in[12];
    const float* eW4 = (const float*)d_in[13], * eb4 = (const float*)d_in[14];
    const float* eW5 = (const float*)d_in[15], * eb5 = (const float*)d_in[16];
    const float* n1W1 = (const float*)d_in[17], * n1b1 = (const float*)d_in[18];
    const float* n1W2 = (const float*)d_in[19], * n1b2 = (const float*)d_in[20];
    const float* n2W1 = (const float*)d_in[21], * n2b1 = (const float*)d_in[22];
    const float* n2W2 = (const float*)d_in[23], * n2b2 = (const float*)d_in[24];
    float* out = (float*)d_out;

    char* ws = (char*)d_ws;
    size_t off = 0;
    auto alc = [&](size_t bytes) { char* p = ws + off; off += (bytes + 255) & ~(size_t)255; return p; };

    float* ssum  = (float*)alc((size_t)NN * 512 * 4);
    float* cnt   = (float*)alc((size_t)NN * 4);
    float* zbias = (float*)alc(1024 * 4);
    float* cbias = (float*)alc(512 * 4);
    f16* u2h     = (f16*)alc((size_t)256 * 256 * 2);      // 64 valid rows, padded to 256
    f16* ubias_e = (f16*)alc((size_t)64 * 1024 * 2);
    f16* ubias_n = (f16*)alc((size_t)64 * 512 * 2);
    f16* eW1t19  = (f16*)alc((size_t)1024 * 64 * 2);
    f16* eW1ut   = (f16*)alc((size_t)1024 * 256 * 2);
    f16* eW2t    = (f16*)alc((size_t)1024 * 1024 * 2);
    f16* eW3t    = (f16*)alc((size_t)1024 * 1024 * 2);
    f16* eW4t    = (f16*)alc((size_t)1024 * 1024 * 2);
    f16* eW5h    = (f16*)alc((size_t)1024 * 512 * 2);     // eW5 as f16 [1024][512]
    f16* combo_t = (f16*)alc((size_t)512 * 1024 * 2);     // (eW5 @ n1W1[9:521])^T as Bt [512][1024]
    f16* n1W1et  = (f16*)alc((size_t)512 * 512 * 2);
    f16* n1W2t   = (f16*)alc((size_t)512 * 512 * 2);
    f16* n2W1et  = (f16*)alc((size_t)512 * 512 * 2);
    f16* n2W1ut  = (f16*)alc((size_t)512 * 256 * 2);
    f16* agg     = (f16*)alc((size_t)20224 * 512 * 2);
    f16* z1      = (f16*)alc((size_t)20224 * 512 * 2);
    size_t fixed = off;

    // chunk region: per-edge = feat64 (128B) + buf1 (2048B) + buf2 (2048B) + ebat (4B)
    size_t per_edge = 64 * 2 + 1024 * 2 + 1024 * 2 + 4;
    size_t avail = ws_size > fixed ? ws_size - fixed : 0;
    long long Cmax = (long long)(avail / per_edge);
    int C;
    if (Cmax >= E_TOTAL)      C = E_TOTAL;
    else if (Cmax >= 16384)   C = (int)((Cmax / 16384) * 16384); // 256-block rounds
    else                      C = (int)((Cmax / 256) * 256);
    if (C < 256) C = 256;

    f16* featc = (f16*)(ws + fixed);
    f16* buf1  = featc + (size_t)C * 64;
    f16* buf2  = buf1 + (size_t)C * 1024;
    int* ebat  = (int*)(buf2 + (size_t)C * 1024);

    // zero ssum, cnt, zbias (contiguous; cbias computed by kernel)
    size_t zlen = (size_t)((char*)zbias - (char*)ssum) + 1024 * 4;
    hipMemsetAsync(ssum, 0, zlen, stream);

    auto wt = [&](const float* W, f16* Wt, int r0, int Ksub, int N, int Kp) {
        size_t tot = (size_t)N * Kp;
        k_wt<<<(unsigned)((tot + 255) / 256), 256, 0, stream>>>(W, Wt, r0, Ksub, N, Kp);
    };
    wt(eW1, eW1t19, 0, 19, 1024, 64);
    wt(eW1, eW1ut, 19, 256, 1024, 256);
    wt(eW2, eW2t, 0, 1024, 1024, 1024);
    wt(eW3, eW3t, 0, 1024, 1024, 1024);
    wt(eW4, eW4t, 0, 1024, 1024, 1024);
    wt(n1W1, n1W1et, 9, 512, 512, 512);
    wt(n1W2, n1W2t, 0, 512, 512, 512);
    wt(n2W1, n2W1et, 9, 512, 512, 512);
    wt(n2W1, n2W1ut, 521, 256, 512, 256);
    k_cvt<<<(1024 * 512 + 255) / 256, 256, 0, stream>>>(eW5, eW5h, 1024 * 512);

    k_u2<<<dim3(4, NGRAPH), 256, 0, stream>>>(u, Wsel, bsel, u2h);
    k_cnt<<<(E_TOTAL + 255) / 256, 256, 0, stream>>>(ei, cnt);
    k_cbias<<<2, 256, 0, stream>>>(n1W1, eb5, n1b1, cbias);

    // u-contribution tables (include the layer bias)
    hgemm8<0,0,0,0><<<dim3(4, 1), 512, 0, stream>>>(64, 1024, 256, u2h, 256, eW1ut,
        ubias_e, 1024, eb1, nullptr, nullptr, nullptr, nullptr, nullptr, nullptr, nullptr);
    hgemm8<0,0,0,0><<<dim3(2, 1), 512, 0, stream>>>(64, 512, 256, u2h, 256, n2W1ut,
        ubias_n, 512, n2b1, nullptr, nullptr, nullptr, nullptr, nullptr, nullptr, nullptr);

    // combo_t[b][a] = sum_c n1W1[9+c][b] * eW5[a][c]
    hgemm8<0,0,0,0><<<dim3(4, 2), 512, 0, stream>>>(512, 1024, 512, n1W1et, 512, eW5h,
        combo_t, 1024, zbias, nullptr, nullptr, nullptr, nullptr, nullptr, nullptr, nullptr);

    for (int e0 = 0; e0 < E_TOTAL; e0 += C) {
        int Ce = E_TOTAL - e0 < C ? E_TOTAL - e0 : C;
        int gy = (Ce + 255) / 256;

        k_gather19<<<(unsigned)(((size_t)Ce * 64 + 255) / 256), 256, 0, stream>>>(
            e0, Ce, x, eattr, ei, batch, featc, ebat);

        hgemm8<1,1,0,0><<<dim3(4, gy), 512, 0, stream>>>(Ce, 1024, 64, featc, 64, eW1t19,
            buf1, 1024, zbias, ubias_e, ebat, nullptr, nullptr, nullptr, nullptr, nullptr);
        hgemm8<1,0,0,0><<<dim3(4, gy), 512, 0, stream>>>(Ce, 1024, 1024, buf1, 1024, eW2t,
            buf2, 1024, eb2, nullptr, nullptr, nullptr, nullptr, nullptr, nullptr, nullptr);
        hgemm8<1,0,0,0><<<dim3(4, gy), 512, 0, stream>>>(Ce, 1024, 1024, buf2, 1024, eW3t,
            buf1, 1024, eb3, nullptr, nullptr, nullptr, nullptr, nullptr, nullptr, nullptr);
        hgemm8<1,0,0,0><<<dim3(4, gy), 512, 0, stream>>>(Ce, 1024, 1024, buf1, 1024, eW4t,
            buf2, 1024, eb4, nullptr, nullptr, nullptr, nullptr, nullptr, nullptr, nullptr);

        // h1 = relu(x[col]@n1W1[0:9] + (buf2)@combo + cbias)   (eW5+n1W1 folded)
        hgemm8<1,0,1,0><<<dim3(2, gy), 512, 0, stream>>>(Ce, 512, 1024, buf2, 1024, combo_t,
            buf1, 512, cbias, nullptr, nullptr, x, ei + E_TOTAL + e0, n1W1, nullptr, nullptr);

        // h2 = relu(h1@n1W2 + n1b2), scatter-add into ssum fused in epilogue
        hgemm8<1,0,0,1><<<dim3(2, gy), 512, 0, stream>>>(Ce, 512, 512, buf1, 512, n1W2t,
            nullptr, 512, n1b2, nullptr, nullptr, nullptr, nullptr, nullptr, ssum, ei + e0);
    }

    // readout
    k_agg<<<(unsigned)(((size_t)NN * 512 + 255) / 256), 256, 0, stream>>>(ssum, cnt, agg);
    hgemm8<1,1,1,0><<<dim3(2, 79), 512, 0, stream>>>(NN, 512, 512, agg, 512, n2W1et,
        z1, 512, zbias, ubias_n, batch, x, nullptr, n2W1, nullptr, nullptr);
    k_final<<<(NN * 64 + 255) / 256, 256, 0, stream>>>(z1, n2W2, n2b2, out);
}

// Round 8
// 2278.876 us; speedup vs baseline: 9.4010x; 1.0302x over previous
//
#include <hip/hip_runtime.h>

typedef _Float16 f16;
typedef __attribute__((ext_vector_type(8))) _Float16 f16x8;
typedef __attribute__((ext_vector_type(4))) float f32x4;

#define E_TOTAL 160000
#define NN 20000
#define NGRAPH 64

__device__ __forceinline__ void gl_lds16(const void* g, void* l) {
    __builtin_amdgcn_global_load_lds((const __attribute__((address_space(1))) void*)g,
                                     (__attribute__((address_space(3))) void*)l, 16, 0, 0);
}

#define MFMA16(a, b, c) __builtin_amdgcn_mfma_f32_16x16x32_f16((a), (b), (c), 0, 0, 0)
#define LGKM0 do { asm volatile("s_waitcnt lgkmcnt(0)" ::: "memory"); \
                   __builtin_amdgcn_sched_barrier(0); } while (0)
#define VMW4  asm volatile("s_waitcnt vmcnt(4)" ::: "memory")
#define VMW0  asm volatile("s_waitcnt vmcnt(0)" ::: "memory")
#define SBAR  __builtin_amdgcn_s_barrier()

// ---------------- fp16 MFMA GEMM, 256x256 tile, BK=64, 8 waves, 4-phase + XCD swizzle --------
// C[M,N] = act(A[M,lda] @ Bt[N,K]^T + bias [+aux]).  K mult of 64, N mult of 256.
// T1: bijective XCD-chunked work remap (m204): each XCD gets a contiguous bm-major run of
// work-items, so the nbn blocks sharing an A-panel execute on ONE XCD -> A fetched once per L2.
// AUXU: += utab[uidx[row]*N+col]  AUXX: += dot(x9[xi*9..], W9[q*N+col])  SCAT: atomicAdd to sout.
template <int RELU, int AUXU, int AUXX, int SCAT>
__global__ __launch_bounds__(512, 2) void hgemm8(
    int M, int N, int K,
    const f16* __restrict__ A, int lda,
    const f16* __restrict__ Bt,
    f16* __restrict__ C, int ldc,
    const float* __restrict__ bias,
    const f16* __restrict__ utab, const int* __restrict__ uidx,
    const float* __restrict__ x9, const int* __restrict__ xidx, const float* __restrict__ W9,
    float* __restrict__ sout, const int* __restrict__ sidx)
{
    __shared__ __align__(16) char Ash[2][2][16384];
    __shared__ __align__(16) char Bsh[2][2][16384];
    __shared__ float Ws9[AUXX ? 2304 : 1];   // 9 x 256

    const int tid  = threadIdx.x;
    const int lane = tid & 63;
    const int w    = tid >> 6;            // 0..7

    // ---- T1: bijective XCD-chunked remap (m204). HW dispatch id d round-robins XCDs (d%8);
    // give XCD k the contiguous work range [base_k, base_k+count_k) in bm-major order.
    const int nbn = gridDim.x;
    const int nwg = nbn * gridDim.y;
    {
    }
    int d  = blockIdx.y * nbn + blockIdx.x;
    int q8 = nwg >> 3, r8 = nwg & 7;
    int xk = d & 7, j8 = d >> 3;
    int wl = (xk < r8 ? xk * (q8 + 1) : r8 * (q8 + 1) + (xk - r8) * q8) + j8;
    const int bm = (wl / nbn) * 256;
    const int bn = (wl % nbn) * 256;

    const int wm = (w >> 2) * 128;        // 2 waves along M
    const int wn = (w & 3) * 64;          // 4 waves along N
    const int fr = lane & 15;
    const int kq = lane >> 4;

    const char* Ab = (const char*)A;
    const char* Bb = (const char*)Bt;
    const size_t lda2 = (size_t)lda * 2;
    const size_t ldb2 = (size_t)K * 2;

    f32x4 acc[8][4] = {};

    // ds_read offsets within a 16KB half-buffer: row r has 64B, slot swizzle s = kq ^ ((r>>1)&3)
    int aoff[8], boff[4];
#pragma unroll
    for (int mi = 0; mi < 8; ++mi) {
        int r = wm + mi * 16 + fr;
        aoff[mi] = r * 64 + ((kq ^ ((r >> 1) & 3)) << 4);
    }
#pragma unroll
    for (int ni = 0; ni < 4; ++ni) {
        int r = wn + ni * 16 + fr;
        boff[ni] = r * 64 + ((kq ^ ((r >> 1) & 3)) << 4);
    }

    // staging: 16KB half-tile = 512 thr x 2 x 16B; LDS linear dest, pre-swizzled global source
    int sdest[2];
    size_t gsrcA[2], gsrcB[2];
#pragma unroll
    for (int i = 0; i < 2; ++i) {
        int L = i * 8192 + tid * 16;
        int row = L >> 6;
        int s = (L >> 4) & 3;
        int sw = (s ^ ((row >> 1) & 3)) << 4;
        sdest[i] = L;
        gsrcA[i] = (size_t)(bm + row) * lda2 + sw;
        gsrcB[i] = (size_t)(bn + row) * ldb2 + sw;
    }

    const int NT = K >> 6;

    auto stageA = [&](int t, int h, int buf) {
        size_t kb = (size_t)t * 128 + h * 64;
#pragma unroll
        for (int i = 0; i < 2; ++i)
            gl_lds16(Ab + gsrcA[i] + kb, &Ash[buf][h][0] + sdest[i]);
    };
    auto stageB = [&](int t, int h, int buf) {
        size_t kb = (size_t)t * 128 + h * 64;
#pragma unroll
        for (int i = 0; i < 2; ++i)
            gl_lds16(Bb + gsrcB[i] + kb, &Bsh[buf][h][0] + sdest[i]);
    };

    // prologue: stage tile 0 (4 half-tiles, consumption order), wait first two
    stageA(0, 0, 0); stageB(0, 0, 0); stageA(0, 1, 0); stageB(0, 1, 0);
    VMW4;
    SBAR;

    for (int t = 0; t < NT; ++t) {
        const int cur = t & 1, nxt = cur ^ 1;
        const bool pre = (t + 1 < NT);
        const char* A0 = &Ash[cur][0][0];
        const char* A1 = &Ash[cur][1][0];
        const char* B0 = &Bsh[cur][0][0];
        const char* B1 = &Bsh[cur][1][0];

        // ---- phase 0: ks=0, mi 0-3 ----
        f16x8 a0[4], b0[4];
#pragma unroll
        for (int i = 0; i < 4; ++i) a0[i] = *(const f16x8*)(A0 + aoff[i]);
#pragma unroll
        for (int i = 0; i < 4; ++i) b0[i] = *(const f16x8*)(B0 + boff[i]);
        if (pre) stageA(t + 1, 0, nxt);
        SBAR;
        LGKM0;
        __builtin_amdgcn_s_setprio(1);
#pragma unroll
        for (int mi = 0; mi < 4; ++mi)
#pragma unroll
            for (int ni = 0; ni < 4; ++ni)
                acc[mi][ni] = MFMA16(a0[mi], b0[ni], acc[mi][ni]);
        __builtin_amdgcn_s_setprio(0);
        SBAR;

        // ---- phase 1: ks=0, mi 4-7 ----
        f16x8 a1[4];
#pragma unroll
        for (int i = 0; i < 4; ++i) a1[i] = *(const f16x8*)(A0 + aoff[4 + i]);
        if (pre) stageB(t + 1, 0, nxt);
        SBAR;
        LGKM0;
        __builtin_amdgcn_s_setprio(1);
#pragma unroll
        for (int mi = 0; mi < 4; ++mi)
#pragma unroll
            for (int ni = 0; ni < 4; ++ni)
                acc[4 + mi][ni] = MFMA16(a1[mi], b0[ni], acc[4 + mi][ni]);
        __builtin_amdgcn_s_setprio(0);
        if (pre) { VMW4; } else { VMW0; }   // A-k1(t), B-k1(t) landed
        SBAR;

        // ---- phase 2: ks=1, mi 0-3 ----
        f16x8 a2[4], b2[4];
#pragma unroll
        for (int i = 0; i < 4; ++i) a2[i] = *(const f16x8*)(A1 + aoff[i]);
#pragma unroll
        for (int i = 0; i < 4; ++i) b2[i] = *(const f16x8*)(B1 + boff[i]);
        if (pre) stageA(t + 1, 1, nxt);
        SBAR;
        LGKM0;
        __builtin_amdgcn_s_setprio(1);
#pragma unroll
        for (int mi = 0; mi < 4; ++mi)
#pragma unroll
            for (int ni = 0; ni < 4; ++ni)
                acc[mi][ni] = MFMA16(a2[mi], b2[ni], acc[mi][ni]);
        __builtin_amdgcn_s_setprio(0);
        SBAR;

        // ---- phase 3: ks=1, mi 4-7 ----
        f16x8 a3[4];
#pragma unroll
        for (int i = 0; i < 4; ++i) a3[i] = *(const f16x8*)(A1 + aoff[4 + i]);
        if (pre) stageB(t + 1, 1, nxt);
        SBAR;
        LGKM0;
        __builtin_amdgcn_s_setprio(1);
#pragma unroll
        for (int mi = 0; mi < 4; ++mi)
#pragma unroll
            for (int ni = 0; ni < 4; ++ni)
                acc[4 + mi][ni] = MFMA16(a3[mi], b2[ni], acc[4 + mi][ni]);
        __builtin_amdgcn_s_setprio(0);
        if (pre) { VMW4; }                  // A-k0(t+1), B-k0(t+1) landed
        SBAR;
    }

    if (AUXX) {
        for (int i = tid; i < 9 * 256; i += 512)
            Ws9[i] = W9[(size_t)(i >> 8) * N + bn + (i & 255)];
        __syncthreads();
    }

    // C/D layout: col = lane&15, row = kq*4 + reg
#pragma unroll
    for (int mi = 0; mi < 8; ++mi) {
        int r0 = bm + wm + mi * 16 + kq * 4;
#pragma unroll
        for (int r = 0; r < 4; ++r) {
            int grow = r0 + r;
            if (grow >= M) continue;
            int ub = 0;
            if (AUXU) ub = uidx[grow];
            int sb = 0;
            if (SCAT) sb = sidx[grow];
            float xv[9];
            if (AUXX) {
                int xi = xidx ? xidx[grow] : grow;
#pragma unroll
                for (int q = 0; q < 9; ++q) xv[q] = x9[(size_t)xi * 9 + q];
            }
#pragma unroll
            for (int ni = 0; ni < 4; ++ni) {
                int lcol = wn + ni * 16 + fr;
                int col = bn + lcol;
                float v = acc[mi][ni][r] + bias[col];
                if (AUXU) v += (float)utab[(size_t)ub * N + col];
                if (AUXX) {
                    float s = 0.f;
#pragma unroll
                    for (int q = 0; q < 9; ++q) s = fmaf(xv[q], Ws9[q * 256 + lcol], s);
                    v += s;
                }
                if (RELU) v = fmaxf(v, 0.f);
                if (SCAT) {
                    atomicAdd(sout + (size_t)sb * N + col, v);
                } else {
                    C[(size_t)grow * ldc + col] = (f16)v;
                }
            }
        }
    }
}

// ---- weight slice transpose: Wt[n][k] = W[(r0+k)*N + n], k<Ksub, pad to Kp with 0 ----
__global__ void k_wt(const float* __restrict__ W, f16* __restrict__ Wt,
                     int r0, int Ksub, int N, int Kp)
{
    size_t t = (size_t)blockIdx.x * 256 + threadIdx.x;
    if (t >= (size_t)N * Kp) return;
    int n = (int)(t / Kp), k = (int)(t % Kp);
    Wt[t] = (k < Ksub) ? (f16)W[(size_t)(r0 + k) * N + n] : (f16)0.f;
}

// ---- plain f32 -> f16 copy ----
__global__ void k_cvt(const float* __restrict__ W, f16* __restrict__ Wt, int n)
{
    int t = blockIdx.x * 256 + threadIdx.x;
    if (t < n) Wt[t] = (f16)W[t];
}

// ---- combo bias: cb[b] = n1b1[b] + sum_c eb5[c] * n1W1[(9+c)*512 + b] ----
__global__ void k_cbias(const float* __restrict__ n1W1, const float* __restrict__ eb5,
                        const float* __restrict__ n1b1, float* __restrict__ cb)
{
    int b = blockIdx.x * 256 + threadIdx.x;
    if (b >= 512) return;
    float s = n1b1[b];
    for (int c = 0; c < 512; ++c) s = fmaf(eb5[c], n1W1[(size_t)(9 + c) * 512 + b], s);
    cb[b] = s;
}

// ---- u2h = f16(u @ Wsel + bsel)  split-K ----
__global__ __launch_bounds__(256) void k_u2(const float* __restrict__ u,
                                            const float* __restrict__ Wsel,
                                            const float* __restrict__ bsel,
                                            f16* __restrict__ u2h)
{
    __shared__ float us[4096];
    __shared__ float red[4][64];
    const int g = blockIdx.y;
    const int c0 = blockIdx.x * 64;
    const int col = threadIdx.x & 63;
    const int kp = threadIdx.x >> 6;
    for (int i = threadIdx.x; i < 4096; i += 256) us[i] = u[(size_t)g * 4096 + i];
    __syncthreads();
    float acc = 0.f;
    for (int k = kp * 1024; k < kp * 1024 + 1024; ++k)
        acc = fmaf(us[k], Wsel[(size_t)k * 256 + c0 + col], acc);
    red[kp][col] = acc;
    __syncthreads();
    if (kp == 0) {
        float v = red[0][col] + red[1][col] + red[2][col] + red[3][col] + bsel[c0 + col];
        u2h[(size_t)g * 256 + c0 + col] = (f16)v;
    }
}

// ---- per-edge gather: feat64 = [x[row](9), x[col](9), ea(1), 0-pad], ebat = batch[row] ----
__global__ void k_gather19(int e0, int Ce,
                           const float* __restrict__ x, const float* __restrict__ eattr,
                           const int* __restrict__ ei, const int* __restrict__ batch,
                           f16* __restrict__ feat, int* __restrict__ ebat)
{
    size_t t = (size_t)blockIdx.x * 256 + threadIdx.x;
    if (t >= (size_t)Ce * 64) return;
    int i = (int)(t >> 6), j = (int)(t & 63);
    int e = e0 + i;
    float v = 0.f;
    if (j < 9)        v = x[ei[e] * 9 + j];
    else if (j < 18)  v = x[ei[E_TOTAL + e] * 9 + (j - 9)];
    else if (j == 18) v = eattr[e];
    else if (j == 19) ebat[i] = batch[ei[e]];
    feat[t] = (f16)v;
}

__global__ void k_cnt(const int* __restrict__ ei, float* __restrict__ cnt)
{
    int t = blockIdx.x * 256 + threadIdx.x;
    if (t < E_TOTAL) atomicAdd(cnt + ei[t], 1.0f);
}

__global__ void k_agg(const float* __restrict__ ssum, const float* __restrict__ cnt,
                      f16* __restrict__ agg)
{
    size_t t = (size_t)blockIdx.x * 256 + threadIdx.x;
    if (t >= (size_t)NN * 512) return;
    int n = (int)(t >> 9);
    agg[t] = (f16)(ssum[t] / fmaxf(cnt[n], 1.f));
}

__global__ void k_final(const f16* __restrict__ z1, const float* __restrict__ W,
                        const float* __restrict__ b, float* __restrict__ out)
{
    int gt = blockIdx.x * 256 + threadIdx.x;
    int row = gt >> 6;
    int lane = threadIdx.x & 63;
    if (row >= NN) return;
    float s = 0.f;
#pragma unroll
    for (int c = lane; c < 512; c += 64) s += (float)z1[(size_t)row * 512 + c] * W[c];
#pragma unroll
    for (int off = 32; off; off >>= 1) s += __shfl_down(s, off);
    if (lane == 0) out[row] = s + b[0];
}

// ---------------- launch ----------------

extern "C" void kernel_launch(void* const* d_in, const int* in_sizes, int n_in,
                              void* d_out, int out_size, void* d_ws, size_t ws_size,
                              hipStream_t stream)
{
    const float* x     = (const float*)d_in[0];
    const float* eattr = (const float*)d_in[1];
    const float* u     = (const float*)d_in[2];
    const int*   ei    = (const int*)d_in[3];
    const int*   batch = (const int*)d_in[4];
    const float* Wsel  = (const float*)d_in[5];
    const float* bsel  = (const float*)d_in[6];
    const float* eW1 = (const float*)d_in[7],  * eb1 = (const float*)d_in[8];
    const float* eW2 = (const float*)d_in[9],  * eb2 = (const float*)d_in[10];
    const float* eW3 = (const float*)d_in[11], * eb3 = (const float*)d_in[12];
    const float* eW4 = (const float*)d_in[13], * eb4 = (const float*)d_in[14];
    const float* eW5 = (const float*)d_in[15], * eb5 = (const float*)d_in[16];
    const float* n1W1 = (const float*)d_in[17], * n1b1 = (const float*)d_in[18];
    const float* n1W2 = (const float*)d_in[19], * n1b2 = (const float*)d_in[20];
    const float* n2W1 = (const float*)d_in[21], * n2b1 = (const float*)d_in[22];
    const float* n2W2 = (const float*)d_in[23], * n2b2 = (const float*)d_in[24];
    float* out = (float*)d_out;

    char* ws = (char*)d_ws;
    size_t off = 0;
    auto alc = [&](size_t bytes) { char* p = ws + off; off += (bytes + 255) & ~(size_t)255; return p; };

    float* ssum  = (float*)alc((size_t)NN * 512 * 4);
    float* cnt   = (float*)alc((size_t)NN * 4);
    float* zbias = (float*)alc(1024 * 4);
    float* cbias = (float*)alc(512 * 4);
    f16* u2h     = (f16*)alc((size_t)256 * 256 * 2);      // 64 valid rows, padded to 256
    f16* ubias_e = (f16*)alc((size_t)64 * 1024 * 2);
    f16* ubias_n = (f16*)alc((size_t)64 * 512 * 2);
    f16* eW1t19  = (f16*)alc((size_t)1024 * 64 * 2);
    f16* eW1ut   = (f16*)alc((size_t)1024 * 256 * 2);
    f16* eW2t    = (f16*)alc((size_t)1024 * 1024 * 2);
    f16* eW3t    = (f16*)alc((size_t)1024 * 1024 * 2);
    f16* eW4t    = (f16*)alc((size_t)1024 * 1024 * 2);
    f16* eW5h    = (f16*)alc((size_t)1024 * 512 * 2);     // eW5 as f16 [1024][512]
    f16* combo_t = (f16*)alc((size_t)512 * 1024 * 2);     // (eW5 @ n1W1[9:521])^T as Bt [512][1024]
    f16* n1W1et  = (f16*)alc((size_t)512 * 512 * 2);
    f16* n1W2t   = (f16*)alc((size_t)512 * 512 * 2);
    f16* n2W1et  = (f16*)alc((size_t)512 * 512 * 2);
    f16* n2W1ut  = (f16*)alc((size_t)512 * 256 * 2);
    f16* agg     = (f16*)alc((size_t)20224 * 512 * 2);
    f16* z1      = (f16*)alc((size_t)20224 * 512 * 2);
    size_t fixed = off;

    // chunk region: per-edge = feat64 (128B) + buf1 (2048B) + buf2 (2048B) + ebat (4B)
    size_t per_edge = 64 * 2 + 1024 * 2 + 1024 * 2 + 4;
    size_t avail = ws_size > fixed ? ws_size - fixed : 0;
    long long Cmax = (long long)(avail / per_edge);
    int C;
    if (Cmax >= E_TOTAL)      C = E_TOTAL;
    else if (Cmax >= 16384)   C = (int)((Cmax / 16384) * 16384); // 256-block rounds
    else                      C = (int)((Cmax / 256) * 256);
    if (C < 256) C = 256;

    f16* featc = (f16*)(ws + fixed);
    f16* buf1  = featc + (size_t)C * 64;
    f16* buf2  = buf1 + (size_t)C * 1024;
    int* ebat  = (int*)(buf2 + (size_t)C * 1024);

    // zero ssum, cnt, zbias (contiguous; cbias computed by kernel)
    size_t zlen = (size_t)((char*)zbias - (char*)ssum) + 1024 * 4;
    hipMemsetAsync(ssum, 0, zlen, stream);

    auto wt = [&](const float* W, f16* Wt, int r0, int Ksub, int N, int Kp) {
        size_t tot = (size_t)N * Kp;
        k_wt<<<(unsigned)((tot + 255) / 256), 256, 0, stream>>>(W, Wt, r0, Ksub, N, Kp);
    };
    wt(eW1, eW1t19, 0, 19, 1024, 64);
    wt(eW1, eW1ut, 19, 256, 1024, 256);
    wt(eW2, eW2t, 0, 1024, 1024, 1024);
    wt(eW3, eW3t, 0, 1024, 1024, 1024);
    wt(eW4, eW4t, 0, 1024, 1024, 1024);
    wt(n1W1, n1W1et, 9, 512, 512, 512);
    wt(n1W2, n1W2t, 0, 512, 512, 512);
    wt(n2W1, n2W1et, 9, 512, 512, 512);
    wt(n2W1, n2W1ut, 521, 256, 512, 256);
    k_cvt<<<(1024 * 512 + 255) / 256, 256, 0, stream>>>(eW5, eW5h, 1024 * 512);

    k_u2<<<dim3(4, NGRAPH), 256, 0, stream>>>(u, Wsel, bsel, u2h);
    k_cnt<<<(E_TOTAL + 255) / 256, 256, 0, stream>>>(ei, cnt);
    k_cbias<<<2, 256, 0, stream>>>(n1W1, eb5, n1b1, cbias);

    // u-contribution tables (include the layer bias)
    hgemm8<0,0,0,0><<<dim3(4, 1), 512, 0, stream>>>(64, 1024, 256, u2h, 256, eW1ut,
        ubias_e, 1024, eb1, nullptr, nullptr, nullptr, nullptr, nullptr, nullptr, nullptr);
    hgemm8<0,0,0,0><<<dim3(2, 1), 512, 0, stream>>>(64, 512, 256, u2h, 256, n2W1ut,
        ubias_n, 512, n2b1, nullptr, nullptr, nullptr, nullptr, nullptr, nullptr, nullptr);

    // combo_t[b][a] = sum_c n1W1[9+c][b] * eW5[a][c]
    hgemm8<0,0,0,0><<<dim3(4, 2), 512, 0, stream>>>(512, 1024, 512, n1W1et, 512, eW5h,
        combo_t, 1024, zbias, nullptr, nullptr, nullptr, nullptr, nullptr, nullptr, nullptr);

    for (int e0 = 0; e0 < E_TOTAL; e0 += C) {
        int Ce = E_TOTAL - e0 < C ? E_TOTAL - e0 : C;
        int gy = (Ce + 255) / 256;

        k_gather19<<<(unsigned)(((size_t)Ce * 64 + 255) / 256), 256, 0, stream>>>(
            e0, Ce, x, eattr, ei, batch, featc, ebat);

        hgemm8<1,1,0,0><<<dim3(4, gy), 512, 0, stream>>>(Ce, 1024, 64, featc, 64, eW1t19,
            buf1, 1024, zbias, ubias_e, ebat, nullptr, nullptr, nullptr, nullptr, nullptr);
        hgemm8<1,0,0,0><<<dim3(4, gy), 512, 0, stream>>>(Ce, 1024, 1024, buf1, 1024, eW2t,
            buf2, 1024, eb2, nullptr, nullptr, nullptr, nullptr, nullptr, nullptr, nullptr);
        hgemm8<1,0,0,0><<<dim3(4, gy), 512, 0, stream>>>(Ce, 1024, 1024, buf2, 1024, eW3t,
            buf1, 1024, eb3, nullptr, nullptr, nullptr, nullptr, nullptr, nullptr, nullptr);
        hgemm8<1,0,0,0><<<dim3(4, gy), 512, 0, stream>>>(Ce, 1024, 1024, buf1, 1024, eW4t,
            buf2, 1024, eb4, nullptr, nullptr, nullptr, nullptr, nullptr, nullptr, nullptr);

        // h1 = relu(x[col]@n1W1[0:9] + (buf2)@combo + cbias)   (eW5+n1W1 folded)
        hgemm8<1,0,1,0><<<dim3(2, gy), 512, 0, stream>>>(Ce, 512, 1024, buf2, 1024, combo_t,
            buf1, 512, cbias, nullptr, nullptr, x, ei + E_TOTAL + e0, n1W1, nullptr, nullptr);

        // h2 = relu(h1@n1W2 + n1b2), scatter-add into ssum fused in epilogue
        hgemm8<1,0,0,1><<<dim3(2, gy), 512, 0, stream>>>(Ce, 512, 512, buf1, 512, n1W2t,
            nullptr, 512, n1b2, nullptr, nullptr, nullptr, nullptr, nullptr, ssum, ei + e0);
    }

    // readout
    k_agg<<<(unsigned)(((size_t)NN * 512 + 255) / 256), 256, 0, stream>>>(ssum, cnt, agg);
    hgemm8<1,1,1,0><<<dim3(2, 79), 512, 0, stream>>>(NN, 512, 512, agg, 512, n2W1et,
        z1, 512, zbias, ubias_n, batch, x, nullptr, n2W1, nullptr, nullptr);
    k_final<<<(NN * 64 + 255) / 256, 256, 0, stream>>>(z1, n2W2, n2b2, out);
}

// Round 9
// 2213.138 us; speedup vs baseline: 9.6802x; 1.0297x over previous
//
#include <hip/hip_runtime.h>

typedef _Float16 f16;
typedef __attribute__((ext_vector_type(8))) _Float16 f16x8;
typedef __attribute__((ext_vector_type(4))) float f32x4;

#define E_TOTAL 160000
#define NN 20000
#define NGRAPH 64

__device__ __forceinline__ void gl_lds16(const void* g, void* l) {
    __builtin_amdgcn_global_load_lds((const __attribute__((address_space(1))) void*)g,
                                     (__attribute__((address_space(3))) void*)l, 16, 0, 0);
}

#define MFMA16(a, b, c) __builtin_amdgcn_mfma_f32_16x16x32_f16((a), (b), (c), 0, 0, 0)
#define LGKM(n) do { asm volatile("s_waitcnt lgkmcnt(" #n ")" ::: "memory"); \
                     __builtin_amdgcn_sched_barrier(0); } while (0)
#define VMW4  asm volatile("s_waitcnt vmcnt(4)" ::: "memory")
#define VMW0  asm volatile("s_waitcnt vmcnt(0)" ::: "memory")
#define SBAR  __builtin_amdgcn_s_barrier()
#define SCHED0 __builtin_amdgcn_sched_barrier(0)

// ------------- fp16 MFMA GEMM, 256x256, BK=64, 8 waves, pipelined-lgkm 4-phase, XCD swizzle ----
// C[M,N] = act(A[M,lda] @ Bt[N,K]^T + bias [+aux]).  K mult of 64, N mult of 256.
// Phase p issues phase p+1's ds_reads; waits are counted (lgkmcnt 4/8, vmcnt 4) so every wait
// targets ops issued >=1 phase earlier.  WAR ledger: stages of buf^1 follow P3's lgkm0+barrier;
// reads of staged data follow each wave's vmcnt drain + barrier (P1, P3).
template <int RELU, int AUXU, int AUXX, int SCAT>
__global__ __launch_bounds__(512, 2) void hgemm8(
    int M, int N, int K,
    const f16* __restrict__ A, int lda,
    const f16* __restrict__ Bt,
    f16* __restrict__ C, int ldc,
    const float* __restrict__ bias,
    const f16* __restrict__ utab, const int* __restrict__ uidx,
    const float* __restrict__ x9, const int* __restrict__ xidx, const float* __restrict__ W9,
    float* __restrict__ sout, const int* __restrict__ sidx)
{
    __shared__ __align__(16) char Ash[2][2][16384];
    __shared__ __align__(16) char Bsh[2][2][16384];
    __shared__ float Ws9[AUXX ? 2304 : 1];   // 9 x 256

    const int tid  = threadIdx.x;
    const int lane = tid & 63;
    const int w    = tid >> 6;            // 0..7

    // T1: bijective XCD-chunked remap (m204)
    const int nbn = gridDim.x;
    const int nwg = nbn * gridDim.y;
    int d  = blockIdx.y * nbn + blockIdx.x;
    int q8 = nwg >> 3, r8 = nwg & 7;
    int xk = d & 7, j8 = d >> 3;
    int wl = (xk < r8 ? xk * (q8 + 1) : r8 * (q8 + 1) + (xk - r8) * q8) + j8;
    const int bm = (wl / nbn) * 256;
    const int bn = (wl % nbn) * 256;

    const int wm = (w >> 2) * 128;        // 2 waves along M
    const int wn = (w & 3) * 64;          // 4 waves along N
    const int fr = lane & 15;
    const int kq = lane >> 4;

    const char* Ab = (const char*)A;
    const char* Bb = (const char*)Bt;
    const size_t lda2 = (size_t)lda * 2;
    const size_t ldb2 = (size_t)K * 2;

    f32x4 acc[8][4] = {};

    // ds_read offsets within a 16KB half-buffer (row=64B, slot swizzle s = kq ^ ((r>>1)&3))
    int aoff[8], boff[4];
#pragma unroll
    for (int mi = 0; mi < 8; ++mi) {
        int r = wm + mi * 16 + fr;
        aoff[mi] = r * 64 + ((kq ^ ((r >> 1) & 3)) << 4);
    }
#pragma unroll
    for (int ni = 0; ni < 4; ++ni) {
        int r = wn + ni * 16 + fr;
        boff[ni] = r * 64 + ((kq ^ ((r >> 1) & 3)) << 4);
    }

    // staging: 16KB half-tile = 512 thr x 2 x 16B; LDS linear-in-lane dest, pre-swizzled src
    int sdest[2];
    size_t gsrcA[2], gsrcB[2];
#pragma unroll
    for (int i = 0; i < 2; ++i) {
        int L = i * 8192 + tid * 16;
        int row = L >> 6;
        int s = (L >> 4) & 3;
        int sw = (s ^ ((row >> 1) & 3)) << 4;
        sdest[i] = L;
        gsrcA[i] = (size_t)(bm + row) * lda2 + sw;
        gsrcB[i] = (size_t)(bn + row) * ldb2 + sw;
    }

    const int NT = K >> 6;

    auto stageA = [&](int t, int h, int buf) {
        size_t kb = (size_t)t * 128 + h * 64;
#pragma unroll
        for (int i = 0; i < 2; ++i)
            gl_lds16(Ab + gsrcA[i] + kb, &Ash[buf][h][0] + sdest[i]);
    };
    auto stageB = [&](int t, int h, int buf) {
        size_t kb = (size_t)t * 128 + h * 64;
#pragma unroll
        for (int i = 0; i < 2; ++i)
            gl_lds16(Bb + gsrcB[i] + kb, &Bsh[buf][h][0] + sdest[i]);
    };

    f16x8 a0[4], b0[4], a1[4], a2[4], b2[4], a3[4];

    // prologue: stage tile 0; wait A0,B0; issue R0(0)
    stageA(0, 0, 0); stageB(0, 0, 0); stageA(0, 1, 0); stageB(0, 1, 0);
    VMW4;
    SBAR;
#pragma unroll
    for (int i = 0; i < 4; ++i) a0[i] = *(const f16x8*)(&Ash[0][0][0] + aoff[i]);
#pragma unroll
    for (int i = 0; i < 4; ++i) b0[i] = *(const f16x8*)(&Bsh[0][0][0] + boff[i]);

    for (int t = 0; t < NT; ++t) {
        const int cur = t & 1, nxt = cur ^ 1;
        const bool pre = (t + 1 < NT);
        const char* A0 = &Ash[cur][0][0];
        const char* A1 = &Ash[cur][1][0];
        const char* B1 = &Bsh[cur][1][0];

        // ---- P0: issue R1 (a1); stage A0(t+1); wait R0; MFMA(a0,b0) ----
#pragma unroll
        for (int i = 0; i < 4; ++i) a1[i] = *(const f16x8*)(A0 + aoff[4 + i]);
        if (pre) stageA(t + 1, 0, nxt);
        SBAR;
        LGKM(4);
        __builtin_amdgcn_s_setprio(1);
#pragma unroll
        for (int mi = 0; mi < 4; ++mi)
#pragma unroll
            for (int ni = 0; ni < 4; ++ni)
                acc[mi][ni] = MFMA16(a0[mi], b0[ni], acc[mi][ni]);
        __builtin_amdgcn_s_setprio(0);
        SBAR;

        // ---- P1: stage B0(t+1); wait R1; drain A1,B1(t); issue R2 (a2,b2); MFMA(a1,b0) ----
        if (pre) stageB(t + 1, 0, nxt);
        SBAR;
        LGKM(0);
        if (pre) { VMW4; } else { VMW0; }
        SBAR;
#pragma unroll
        for (int i = 0; i < 4; ++i) a2[i] = *(const f16x8*)(A1 + aoff[i]);
#pragma unroll
        for (int i = 0; i < 4; ++i) b2[i] = *(const f16x8*)(B1 + boff[i]);
        SCHED0;
        __builtin_amdgcn_s_setprio(1);
#pragma unroll
        for (int mi = 0; mi < 4; ++mi)
#pragma unroll
            for (int ni = 0; ni < 4; ++ni)
                acc[4 + mi][ni] = MFMA16(a1[mi], b0[ni], acc[4 + mi][ni]);
        __builtin_amdgcn_s_setprio(0);
        SBAR;

        // ---- P2: issue R3 (a3); stage A1(t+1); wait R2; MFMA(a2,b2) ----
#pragma unroll
        for (int i = 0; i < 4; ++i) a3[i] = *(const f16x8*)(A1 + aoff[4 + i]);
        if (pre) stageA(t + 1, 1, nxt);
        SBAR;
        LGKM(4);
        __builtin_amdgcn_s_setprio(1);
#pragma unroll
        for (int mi = 0; mi < 4; ++mi)
#pragma unroll
            for (int ni = 0; ni < 4; ++ni)
                acc[mi][ni] = MFMA16(a2[mi], b2[ni], acc[mi][ni]);
        __builtin_amdgcn_s_setprio(0);
        SBAR;

        // ---- P3: stage B1(t+1); wait R3; drain A0,B0(t+1); issue R0(t+1); MFMA(a3,b2) ----
        if (pre) stageB(t + 1, 1, nxt);
        SBAR;
        LGKM(0);
        if (pre) {
            VMW4;
            SBAR;
            const char* An = &Ash[nxt][0][0];
            const char* Bn = &Bsh[nxt][0][0];
#pragma unroll
            for (int i = 0; i < 4; ++i) a0[i] = *(const f16x8*)(An + aoff[i]);
#pragma unroll
            for (int i = 0; i < 4; ++i) b0[i] = *(const f16x8*)(Bn + boff[i]);
            SCHED0;
        }
        __builtin_amdgcn_s_setprio(1);
#pragma unroll
        for (int mi = 0; mi < 4; ++mi)
#pragma unroll
            for (int ni = 0; ni < 4; ++ni)
                acc[4 + mi][ni] = MFMA16(a3[mi], b2[ni], acc[4 + mi][ni]);
        __builtin_amdgcn_s_setprio(0);
        SBAR;
    }

    if (AUXX) {
        for (int i = tid; i < 9 * 256; i += 512)
            Ws9[i] = W9[(size_t)(i >> 8) * N + bn + (i & 255)];
        __syncthreads();
    }

    // C/D layout: col = lane&15, row = kq*4 + reg
#pragma unroll
    for (int mi = 0; mi < 8; ++mi) {
        int r0 = bm + wm + mi * 16 + kq * 4;
#pragma unroll
        for (int r = 0; r < 4; ++r) {
            int grow = r0 + r;
            if (grow >= M) continue;
            int ub = 0;
            if (AUXU) ub = uidx[grow];
            int sb = 0;
            if (SCAT) sb = sidx[grow];
            float xv[9];
            if (AUXX) {
                int xi = xidx ? xidx[grow] : grow;
#pragma unroll
                for (int q = 0; q < 9; ++q) xv[q] = x9[(size_t)xi * 9 + q];
            }
#pragma unroll
            for (int ni = 0; ni < 4; ++ni) {
                int lcol = wn + ni * 16 + fr;
                int col = bn + lcol;
                float v = acc[mi][ni][r] + bias[col];
                if (AUXU) v += (float)utab[(size_t)ub * N + col];
                if (AUXX) {
                    float s = 0.f;
#pragma unroll
                    for (int q = 0; q < 9; ++q) s = fmaf(xv[q], Ws9[q * 256 + lcol], s);
                    v += s;
                }
                if (RELU) v = fmaxf(v, 0.f);
                if (SCAT) {
                    atomicAdd(sout + (size_t)sb * N + col, v);
                } else {
                    C[(size_t)grow * ldc + col] = (f16)v;
                }
            }
        }
    }
}

// ---- merged weight prep: 10 jobs in one dispatch ----
struct WtJob { const float* src; f16* dst; int r0, ks, n, kp, tr; };
struct WtJobs { WtJob j[10]; };

__global__ void k_wtall(WtJobs js)
{
    WtJob jb = js.j[blockIdx.y];
    size_t tot = (size_t)jb.n * jb.kp;
    size_t t = (size_t)blockIdx.x * 256 + threadIdx.x;
    if (t >= tot) return;
    if (jb.tr) {
        int n = (int)(t / jb.kp), k = (int)(t % jb.kp);
        jb.dst[t] = (k < jb.ks) ? (f16)jb.src[(size_t)(jb.r0 + k) * jb.n + n] : (f16)0.f;
    } else {
        jb.dst[t] = (f16)jb.src[t];
    }
}

// ---- combo bias: cb[b] = n1b1[b] + sum_c eb5[c] * n1W1[(9+c)*512 + b] ----
__global__ void k_cbias(const float* __restrict__ n1W1, const float* __restrict__ eb5,
                        const float* __restrict__ n1b1, float* __restrict__ cb)
{
    int b = blockIdx.x * 256 + threadIdx.x;
    if (b >= 512) return;
    float s = n1b1[b];
    for (int c = 0; c < 512; ++c) s = fmaf(eb5[c], n1W1[(size_t)(9 + c) * 512 + b], s);
    cb[b] = s;
}

// ---- u2h = f16(u @ Wsel + bsel): grid (16 colblk, 64 graphs), 16 cols x 16 kparts ----
__global__ __launch_bounds__(256) void k_u2b(const float* __restrict__ u,
                                             const float* __restrict__ Wsel,
                                             const float* __restrict__ bsel,
                                             f16* __restrict__ u2h)
{
    __shared__ float us[4096];
    __shared__ float red[256];
    const int g = blockIdx.y;
    const int c0 = blockIdx.x * 16;
    const int col = threadIdx.x & 15;
    const int kp = threadIdx.x >> 4;
    for (int i = threadIdx.x; i < 4096; i += 256) us[i] = u[(size_t)g * 4096 + i];
    __syncthreads();
    float acc = 0.f;
    const float* wp = Wsel + (size_t)(kp * 256) * 256 + c0 + col;
#pragma unroll 8
    for (int i = 0; i < 256; ++i) acc = fmaf(us[kp * 256 + i], wp[(size_t)i * 256], acc);
    red[threadIdx.x] = acc;
    __syncthreads();
    if (kp < 8) red[threadIdx.x] += red[threadIdx.x + 128];
    __syncthreads();
    if (kp < 4) red[threadIdx.x] += red[threadIdx.x + 64];
    __syncthreads();
    if (kp < 2) red[threadIdx.x] += red[threadIdx.x + 32];
    __syncthreads();
    if (kp == 0)
        u2h[(size_t)g * 256 + c0 + col] = (f16)(red[threadIdx.x] + red[threadIdx.x + 16] + bsel[c0 + col]);
}

// ---- per-edge gather (all edges): feat64 = [x[row](9), x[col](9), ea(1), pad], ebat ----
__global__ void k_gather19(const float* __restrict__ x, const float* __restrict__ eattr,
                           const int* __restrict__ ei, const int* __restrict__ batch,
                           f16* __restrict__ feat, int* __restrict__ ebat)
{
    size_t t = (size_t)blockIdx.x * 256 + threadIdx.x;
    if (t >= (size_t)E_TOTAL * 64) return;
    int i = (int)(t >> 6), j = (int)(t & 63);
    float v = 0.f;
    if (j < 9)        v = x[ei[i] * 9 + j];
    else if (j < 18)  v = x[ei[E_TOTAL + i] * 9 + (j - 9)];
    else if (j == 18) v = eattr[i];
    else if (j == 19) ebat[i] = batch[ei[i]];
    feat[t] = (f16)v;
}

__global__ void k_cnt(const int* __restrict__ ei, float* __restrict__ cnt)
{
    int t = blockIdx.x * 256 + threadIdx.x;
    if (t < E_TOTAL) atomicAdd(cnt + ei[t], 1.0f);
}

__global__ void k_agg(const float* __restrict__ ssum, const float* __restrict__ cnt,
                      f16* __restrict__ agg)
{
    size_t t = (size_t)blockIdx.x * 256 + threadIdx.x;
    if (t >= (size_t)NN * 512) return;
    int n = (int)(t >> 9);
    agg[t] = (f16)(ssum[t] / fmaxf(cnt[n], 1.f));
}

__global__ void k_final(const f16* __restrict__ z1, const float* __restrict__ W,
                        const float* __restrict__ b, float* __restrict__ out)
{
    int gt = blockIdx.x * 256 + threadIdx.x;
    int row = gt >> 6;
    int lane = threadIdx.x & 63;
    if (row >= NN) return;
    float s = 0.f;
#pragma unroll
    for (int c = lane; c < 512; c += 64) s += (float)z1[(size_t)row * 512 + c] * W[c];
#pragma unroll
    for (int off = 32; off; off >>= 1) s += __shfl_down(s, off);
    if (lane == 0) out[row] = s + b[0];
}

// ---------------- launch ----------------

extern "C" void kernel_launch(void* const* d_in, const int* in_sizes, int n_in,
                              void* d_out, int out_size, void* d_ws, size_t ws_size,
                              hipStream_t stream)
{
    const float* x     = (const float*)d_in[0];
    const float* eattr = (const float*)d_in[1];
    const float* u     = (const float*)d_in[2];
    const int*   ei    = (const int*)d_in[3];
    const int*   batch = (const int*)d_in[4];
    const float* Wsel  = (const float*)d_in[5];
    const float* bsel  = (const float*)d_in[6];
    const float* eW1 = (const float*)d_in[7],  * eb1 = (const float*)d_in[8];
    const float* eW2 = (const float*)d_in[9],  * eb2 = (const float*)d_in[10];
    const float* eW3 = (const float*)d_in[11], * eb3 = (const float*)d_in[12];
    const float* eW4 = (const float*)d_in[13], * eb4 = (const float*)d_in[14];
    const float* eW5 = (const float*)d_in[15], * eb5 = (const float*)d_in[16];
    const float* n1W1 = (const float*)d_in[17], * n1b1 = (const float*)d_in[18];
    const float* n1W2 = (const float*)d_in[19], * n1b2 = (const float*)d_in[20];
    const float* n2W1 = (const float*)d_in[21], * n2b1 = (const float*)d_in[22];
    const float* n2W2 = (const float*)d_in[23], * n2b2 = (const float*)d_in[24];
    float* out = (float*)d_out;

    char* ws = (char*)d_ws;
    size_t off = 0;
    auto alc = [&](size_t bytes) { char* p = ws + off; off += (bytes + 255) & ~(size_t)255; return p; };

    float* ssum  = (float*)alc((size_t)NN * 512 * 4);
    float* cnt   = (float*)alc((size_t)NN * 4);
    float* zbias = (float*)alc(1024 * 4);
    float* cbias = (float*)alc(512 * 4);
    f16* u2h     = (f16*)alc((size_t)256 * 256 * 2);
    f16* ubias_e = (f16*)alc((size_t)64 * 1024 * 2);
    f16* ubias_n = (f16*)alc((size_t)64 * 512 * 2);
    f16* eW1t19  = (f16*)alc((size_t)1024 * 64 * 2);
    f16* eW1ut   = (f16*)alc((size_t)1024 * 256 * 2);
    f16* eW2t    = (f16*)alc((size_t)1024 * 1024 * 2);
    f16* eW3t    = (f16*)alc((size_t)1024 * 1024 * 2);
    f16* eW4t    = (f16*)alc((size_t)1024 * 1024 * 2);
    f16* eW5h    = (f16*)alc((size_t)1024 * 512 * 2);
    f16* combo_t = (f16*)alc((size_t)512 * 1024 * 2);
    f16* n1W1et  = (f16*)alc((size_t)512 * 512 * 2);
    f16* n1W2t   = (f16*)alc((size_t)512 * 512 * 2);
    f16* n2W1et  = (f16*)alc((size_t)512 * 512 * 2);
    f16* n2W1ut  = (f16*)alc((size_t)512 * 256 * 2);
    f16* featAll = (f16*)alc((size_t)E_TOTAL * 64 * 2);
    int* ebatAll = (int*)alc((size_t)E_TOTAL * 4);
    size_t fixed = off;

    // chunk region: per-edge = buf1 (2048B) + buf2 (2048B); agg/z1 alias this region post-loop
    size_t per_edge = 4096;
    size_t need_ro = (size_t)20224 * 512 * 2 * 2;   // agg + z1
    size_t avail = ws_size > fixed ? ws_size - fixed : 0;
    long long Cmax = (long long)(avail / per_edge);
    int C;
    if (Cmax >= E_TOTAL)      C = E_TOTAL;
    else if (Cmax >= 16384)   C = (int)((Cmax / 16384) * 16384);
    else                      C = (int)((Cmax / 256) * 256);
    if ((size_t)C * per_edge < need_ro)
        C = (int)(((need_ro + per_edge - 1) / per_edge + 255) / 256 * 256);

    f16* buf1 = (f16*)(ws + fixed);
    f16* buf2 = buf1 + (size_t)C * 1024;
    f16* agg  = (f16*)(ws + fixed);                 // alias (used after chunk loop)
    f16* z1   = agg + (size_t)20224 * 512;

    // zero ssum, cnt, zbias, cbias (contiguous)
    size_t zlen = (size_t)((char*)cbias - (char*)ssum) + 512 * 4;
    hipMemsetAsync(ssum, 0, zlen, stream);

    // merged weight prep (one dispatch)
    WtJobs js;
    js.j[0] = {eW1,  eW1t19, 0,   19,   1024, 64,   1};
    js.j[1] = {eW1,  eW1ut,  19,  256,  1024, 256,  1};
    js.j[2] = {eW2,  eW2t,   0,   1024, 1024, 1024, 1};
    js.j[3] = {eW3,  eW3t,   0,   1024, 1024, 1024, 1};
    js.j[4] = {eW4,  eW4t,   0,   1024, 1024, 1024, 1};
    js.j[5] = {n1W1, n1W1et, 9,   512,  512,  512,  1};
    js.j[6] = {n1W2, n1W2t,  0,   512,  512,  512,  1};
    js.j[7] = {n2W1, n2W1et, 9,   512,  512,  512,  1};
    js.j[8] = {n2W1, n2W1ut, 521, 256,  512,  256,  1};
    js.j[9] = {eW5,  eW5h,   0,   0,    1024, 512,  0};  // flat f32->f16 copy
    k_wtall<<<dim3(4096, 10), 256, 0, stream>>>(js);

    k_u2b<<<dim3(16, NGRAPH), 256, 0, stream>>>(u, Wsel, bsel, u2h);
    k_cnt<<<(E_TOTAL + 255) / 256, 256, 0, stream>>>(ei, cnt);
    k_cbias<<<2, 256, 0, stream>>>(n1W1, eb5, n1b1, cbias);
    k_gather19<<<(unsigned)(((size_t)E_TOTAL * 64 + 255) / 256), 256, 0, stream>>>(
        x, eattr, ei, batch, featAll, ebatAll);

    // u-contribution tables (include the layer bias)
    hgemm8<0,0,0,0><<<dim3(4, 1), 512, 0, stream>>>(64, 1024, 256, u2h, 256, eW1ut,
        ubias_e, 1024, eb1, nullptr, nullptr, nullptr, nullptr, nullptr, nullptr, nullptr);
    hgemm8<0,0,0,0><<<dim3(2, 1), 512, 0, stream>>>(64, 512, 256, u2h, 256, n2W1ut,
        ubias_n, 512, n2b1, nullptr, nullptr, nullptr, nullptr, nullptr, nullptr, nullptr);

    // combo_t[b][a] = sum_c n1W1[9+c][b] * eW5[a][c]
    hgemm8<0,0,0,0><<<dim3(4, 2), 512, 0, stream>>>(512, 1024, 512, n1W1et, 512, eW5h,
        combo_t, 1024, zbias, nullptr, nullptr, nullptr, nullptr, nullptr, nullptr, nullptr);

    for (int e0 = 0; e0 < E_TOTAL; e0 += C) {
        int Ce = E_TOTAL - e0 < C ? E_TOTAL - e0 : C;
        int gy = (Ce + 255) / 256;

        hgemm8<1,1,0,0><<<dim3(4, gy), 512, 0, stream>>>(Ce, 1024, 64,
            featAll + (size_t)e0 * 64, 64, eW1t19,
            buf1, 1024, zbias, ubias_e, ebatAll + e0, nullptr, nullptr, nullptr, nullptr, nullptr);
        hgemm8<1,0,0,0><<<dim3(4, gy), 512, 0, stream>>>(Ce, 1024, 1024, buf1, 1024, eW2t,
            buf2, 1024, eb2, nullptr, nullptr, nullptr, nullptr, nullptr, nullptr, nullptr);
        hgemm8<1,0,0,0><<<dim3(4, gy), 512, 0, stream>>>(Ce, 1024, 1024, buf2, 1024, eW3t,
            buf1, 1024, eb3, nullptr, nullptr, nullptr, nullptr, nullptr, nullptr, nullptr);
        hgemm8<1,0,0,0><<<dim3(4, gy), 512, 0, stream>>>(Ce, 1024, 1024, buf1, 1024, eW4t,
            buf2, 1024, eb4, nullptr, nullptr, nullptr, nullptr, nullptr, nullptr, nullptr);

        // h1 = relu(x[col]@n1W1[0:9] + (buf2)@combo + cbias)   (eW5+n1W1 folded)
        hgemm8<1,0,1,0><<<dim3(2, gy), 512, 0, stream>>>(Ce, 512, 1024, buf2, 1024, combo_t,
            buf1, 512, cbias, nullptr, nullptr, x, ei + E_TOTAL + e0, n1W1, nullptr, nullptr);

        // h2 = relu(h1@n1W2 + n1b2), scatter-add into ssum fused in epilogue
        hgemm8<1,0,0,1><<<dim3(2, gy), 512, 0, stream>>>(Ce, 512, 512, buf1, 512, n1W2t,
            nullptr, 512, n1b2, nullptr, nullptr, nullptr, nullptr, nullptr, ssum, ei + e0);
    }

    // readout
    k_agg<<<(unsigned)(((size_t)NN * 512 + 255) / 256), 256, 0, stream>>>(ssum, cnt, agg);
    hgemm8<1,1,1,0><<<dim3(2, 79), 512, 0, stream>>>(NN, 512, 512, agg, 512, n2W1et,
        z1, 512, zbias, ubias_n, batch, x, nullptr, n2W1, nullptr, nullptr);
    k_final<<<(NN * 64 + 255) / 256, 256, 0, stream>>>(z1, n2W2, n2b2, out);
}